// Round 13
// baseline (248.292 us; speedup 1.0000x reference)
//
#include <hip/hip_runtime.h>

#define B_ 2
#define S_ 2048
#define D_ 2048
#define NH 16
#define NKV 8
#define HD 128
#define SCALE 0.08838834764831845f
#define CEXP 0.1275255f          // SCALE * log2(e)
#define RTHR 62.733f             // 8 / CEXP  (defer-max threshold, p <= 2^8)

typedef unsigned short u16;
typedef __attribute__((ext_vector_type(8))) short short8;
typedef __attribute__((ext_vector_type(4))) float f32x4;
typedef __attribute__((ext_vector_type(16))) float f32x16;
typedef __attribute__((ext_vector_type(4))) int i32x4;
typedef __attribute__((ext_vector_type(2))) int i32x2;

#define ASM_VMCNT(N) asm volatile("s_waitcnt vmcnt(" #N ")" ::: "memory")
#define MEMFENCE asm volatile("" ::: "memory")

__device__ __forceinline__ u16 f2b(float f) {
  union { float f; unsigned u; } c; c.f = f;
  unsigned u = c.u;
  return (u16)((u + 0x7fffu + ((u >> 16) & 1u)) >> 16);
}
__device__ __forceinline__ float b2f(u16 h) {
  union { unsigned u; float f; } c; c.u = ((unsigned)h) << 16;
  return c.f;
}
__device__ __forceinline__ float exp2f_fast(float x) {
  float r; asm("v_exp_f32 %0, %1" : "=v"(r) : "v"(x)); return r;
}
__device__ __forceinline__ int cvtpk(float a, float b) {  // low16=bf16(a), high16=bf16(b)
  int r; asm("v_cvt_pk_bf16_f32 %0, %1, %2" : "=v"(r) : "v"(a), "v"(b)); return r;
}
// swap: a.hi32lanes <-> b.lo32lanes (both regs updated)
__device__ __forceinline__ void pl32swap(int& a, int& b) {
  asm volatile("v_permlane32_swap_b32 %0, %1" : "+v"(a), "+v"(b));
}

__device__ __forceinline__ void load_lds16(const u16* g, u16* l) {
  __builtin_amdgcn_global_load_lds(
      (const __attribute__((address_space(1))) unsigned int*)g,
      (__attribute__((address_space(3))) unsigned int*)l, 16, 0, 0);
}

// ---------------- fused f32 -> bf16 conversion (all 5 tensors, 1 launch) ----------------
__global__ __launch_bounds__(256) void cvt_all(const float* __restrict__ x,
                                               const float* __restrict__ wq,
                                               const float* __restrict__ wk,
                                               const float* __restrict__ wv,
                                               const float* __restrict__ wo,
                                               u16* __restrict__ xb,
                                               u16* __restrict__ wqkvb,
                                               u16* __restrict__ wob) {
  const int blk = blockIdx.x;
  const float* src; u16* dst; int base;
  if (blk < 8192)       { src = x;  dst = xb;                  base = blk; }
  else if (blk < 12288) { src = wq; dst = wqkvb;               base = blk - 8192; }
  else if (blk < 14336) { src = wk; dst = wqkvb + 2048 * 2048; base = blk - 12288; }
  else if (blk < 16384) { src = wv; dst = wqkvb + 3072 * 2048; base = blk - 14336; }
  else                  { src = wo; dst = wob;                 base = blk - 16384; }
  int i = base * 256 + threadIdx.x;
  float4 v = ((const float4*)src)[i];
  u16 o0 = f2b(v.x), o1 = f2b(v.y), o2 = f2b(v.z), o3 = f2b(v.w);
  unsigned long long packed = (unsigned long long)o0 | ((unsigned long long)o1 << 16) |
                              ((unsigned long long)o2 << 32) | ((unsigned long long)o3 << 48);
  ((unsigned long long*)dst)[i] = packed;
}

// ---------------- QKV GEMM: 256x128 tile, 8 waves (4Mx2N), single-buffer LDS, 2 blocks/CU --
#define LDA4Q(dst, SRC) \
  { _Pragma("unroll") for (int i2 = 0; i2 < 4; ++i2) { \
      const int arow = wr * 64 + i2 * 16 + r; \
      dst[i2] = *(const short8*)&(SRC)[arow * 32 + ((hi ^ ((arow >> 1) & 3)) << 3)]; } }
#define LDB4Q(dst, SRC) \
  { _Pragma("unroll") for (int n2 = 0; n2 < 4; ++n2) { \
      const int brow = wc * 64 + n2 * 16 + r; \
      dst[n2] = *(const short8*)&(SRC)[brow * 32 + ((hi ^ ((brow >> 1) & 3)) << 3)]; } }
#define MFMA16Q(AF, BF) \
  { __builtin_amdgcn_s_setprio(1); \
    _Pragma("unroll") for (int i2 = 0; i2 < 4; ++i2) \
    _Pragma("unroll") for (int n2 = 0; n2 < 4; ++n2) \
      acc[i2][n2] = __builtin_amdgcn_mfma_f32_16x16x32_bf16(AF[i2], BF[n2], acc[i2][n2], 0, 0, 0); \
    __builtin_amdgcn_s_setprio(0); }

__global__ __launch_bounds__(512, 4) void gemm256x128(const u16* __restrict__ A,
                                                      const u16* __restrict__ Bm,
                                                      u16* __restrict__ C) {
  __shared__ __align__(16) u16 As2[2][8192];   // [kc][256 rows x 32 k]  32 KB
  __shared__ __align__(16) u16 Bs2[2][4096];   // [kc][128 rows x 32 k]  16 KB
  const int tid = threadIdx.x;
  const int wave = tid >> 6, lane = tid & 63;
  const int L = (blockIdx.x & 7) * 64 + (blockIdx.x >> 3);  // bijective XCD chunking
  const int bm = L >> 5, bn = L & 31;          // 16 x 32 tile grid
  const int wr = wave >> 1, wc = wave & 1;     // 4M x 2N waves; per-wave 64x64
  const int r = lane & 15, hi = lane >> 4;
  const int rowA0 = bm * 256, rowB0 = bn * 128;

  f32x4 acc[4][4];
#pragma unroll
  for (int mi = 0; mi < 4; ++mi)
#pragma unroll
    for (int ni = 0; ni < 4; ++ni) acc[mi][ni] = (f32x4){0.f, 0.f, 0.f, 0.f};

  auto stage_ha = [&](u16* lds, int kcol) {
#pragma unroll
    for (int l = 0; l < 2; ++l) {
      const int p = wave * 2048 + l * 1024 + lane * 16;
      const int row = p >> 6, slot = (p >> 4) & 3;
      const int kg = slot ^ ((row >> 1) & 3);
      load_lds16(A + (size_t)(rowA0 + row) * 2048 + kcol + kg * 8,
                 lds + ((wave * 2048 + l * 1024) >> 1));
    }
  };
  auto stage_hb = [&](u16* lds, int kcol) {
    const int p = wave * 1024 + lane * 16;
    const int row = p >> 6, slot = (p >> 4) & 3;
    const int kg = slot ^ ((row >> 1) & 3);
    load_lds16(Bm + (size_t)(rowB0 + row) * 2048 + kcol + kg * 8,
               lds + ((wave * 1024) >> 1));
  };

  for (int kt = 0; kt < 32; ++kt) {
    const int k0 = kt << 6;
    stage_ha(As2[0], k0);
    stage_hb(Bs2[0], k0);
    stage_ha(As2[1], k0 + 32);
    stage_hb(Bs2[1], k0 + 32);
    ASM_VMCNT(0);
    __builtin_amdgcn_s_barrier();
    MEMFENCE;
    short8 af[4], bf[4];
    LDB4Q(bf, Bs2[0]); LDA4Q(af, As2[0]);
    MFMA16Q(af, bf);
    LDB4Q(bf, Bs2[1]); LDA4Q(af, As2[1]);
    MFMA16Q(af, bf);
    MEMFENCE;
    __builtin_amdgcn_s_barrier();   // all reads done before next stage overwrites
  }

#pragma unroll
  for (int mi = 0; mi < 4; ++mi)
#pragma unroll
    for (int ni = 0; ni < 4; ++ni)
#pragma unroll
      for (int r2 = 0; r2 < 4; ++r2) {
        int grow = bm * 256 + wr * 64 + mi * 16 + hi * 4 + r2;
        int gcol = bn * 128 + wc * 64 + ni * 16 + r;
        C[(size_t)grow * 4096 + gcol] = f2b(acc[mi][ni][r2]);
      }
}

// ---------------- GEMM v2 (128^2): kept for the N=2048 output GEMM ----------------
template<int OUTF32>
__global__ __launch_bounds__(256, 2) void gemm_bt2(const u16* __restrict__ A, const u16* __restrict__ Bm,
                                                   void* __restrict__ Cv, int M, int N, int K, int nbn) {
  __shared__ __align__(16) u16 As[2][128 * 64];
  __shared__ __align__(16) u16 Bs[2][128 * 64];
  const int tid = threadIdx.x;
  const int wave = tid >> 6, lane = tid & 63;
  const int nwg = gridDim.x, cpx = nwg >> 3;
  const int L = (blockIdx.x & 7) * cpx + (blockIdx.x >> 3);
  const int bm = L / nbn, bn = L % nbn;
  const int wr = wave >> 1, wc = wave & 1;
  const int r = lane & 15, hi = lane >> 4;

  f32x4 acc[4][4];
#pragma unroll
  for (int m = 0; m < 4; ++m)
#pragma unroll
    for (int n = 0; n < 4; ++n) acc[m][n] = (f32x4){0.f, 0.f, 0.f, 0.f};

  const int gslot = (lane & 7) ^ (lane >> 3);
  const int srow = lane >> 3;

  auto stage = [&](int buf, int k0) {
#pragma unroll
    for (int jj = 0; jj < 4; ++jj) {
      int j = wave * 4 + jj;
      int row = j * 8 + srow;
      load_lds16(A + (size_t)(bm * 128 + row) * K + k0 + gslot * 8, &As[buf][j * 512]);
      load_lds16(Bm + (size_t)(bn * 128 + row) * K + k0 + gslot * 8, &Bs[buf][j * 512]);
    }
  };

  const int nk = K >> 6;
  stage(0, 0);
  for (int kt = 0; kt < nk; ++kt) {
    if (kt + 1 < nk) {
      stage((kt + 1) & 1, (kt + 1) << 6);
      ASM_VMCNT(8);
    } else {
      ASM_VMCNT(0);
    }
    __builtin_amdgcn_s_barrier();
    MEMFENCE;
    const u16* as = As[kt & 1];
    const u16* bs = Bs[kt & 1];
#pragma unroll
    for (int kc = 0; kc < 2; ++kc) {
      short8 af[4], bfr[4];
#pragma unroll
      for (int m = 0; m < 4; ++m) {
        int row = wr * 64 + m * 16 + r;
        int slot = (hi + kc * 4) ^ (row & 7);
        af[m] = *(const short8*)&as[row * 64 + slot * 8];
      }
#pragma unroll
      for (int n = 0; n < 4; ++n) {
        int row = wc * 64 + n * 16 + r;
        int slot = (hi + kc * 4) ^ (row & 7);
        bfr[n] = *(const short8*)&bs[row * 64 + slot * 8];
      }
#pragma unroll
      for (int m = 0; m < 4; ++m)
#pragma unroll
        for (int n = 0; n < 4; ++n)
          acc[m][n] = __builtin_amdgcn_mfma_f32_16x16x32_bf16(af[m], bfr[n], acc[m][n], 0, 0, 0);
    }
    MEMFENCE;
    __builtin_amdgcn_s_barrier();
  }

#pragma unroll
  for (int m = 0; m < 4; ++m)
#pragma unroll
    for (int n = 0; n < 4; ++n)
#pragma unroll
      for (int r2 = 0; r2 < 4; ++r2) {
        int grow = bm * 128 + wr * 64 + m * 16 + hi * 4 + r2;
        int gcol = bn * 128 + wc * 64 + n * 16 + r;
        if (OUTF32)
          ((float*)Cv)[(size_t)grow * N + gcol] = acc[m][n][r2];
        else
          ((u16*)Cv)[(size_t)grow * N + gcol] = f2b(acc[m][n][r2]);
      }
}

// ---------------- per-head RMSNorm + RoPE for Q and K ----------------
__global__ __launch_bounds__(256) void rmsnorm_rope(const u16* __restrict__ qkv, const float* __restrict__ fc,
                                                    const float* __restrict__ qw, const float* __restrict__ kw,
                                                    u16* __restrict__ qr, u16* __restrict__ kr) {
  const int tid = threadIdx.x, wave = tid >> 6, lane = tid & 63;
  const int rowid = blockIdx.x * 4 + wave;
  const int token = rowid / 24;
  const int hh = rowid % 24;
  const int b = token >> 11, s = token & 2047;
  const bool isq = hh < 16;
  const int off = isq ? hh * 128 : 2048 + (hh - 16) * 128;
  const u16* src = qkv + (size_t)token * 4096 + off + lane * 2;
  unsigned pv = *(const unsigned*)src;
  float t0 = b2f((u16)(pv & 0xffffu));
  float t1 = b2f((u16)(pv >> 16));
  float ss = t0 * t0 + t1 * t1;
#pragma unroll
  for (int mm = 1; mm < 64; mm <<= 1) ss += __shfl_xor(ss, mm, 64);
  float rms = rsqrtf(ss * (1.0f / 128.0f) + 1e-6f);
  const float* nw = isq ? qw : kw;
  t0 *= rms * nw[lane * 2];
  t1 *= rms * nw[lane * 2 + 1];
  float c = fc[(s * 64 + lane) * 2], sn = fc[(s * 64 + lane) * 2 + 1];
  float o0 = t0 * c - t1 * sn;
  float o1 = t0 * sn + t1 * c;
  unsigned ov = (unsigned)f2b(o0) | ((unsigned)f2b(o1) << 16);
  if (isq)
    *(unsigned*)(qr + ((size_t)(b * 16 + hh) * 2048 + s) * 128 + lane * 2) = ov;
  else
    *(unsigned*)(kr + ((size_t)(b * 8 + hh - 16) * 2048 + s) * 128 + lane * 2) = ov;
}

// ---------------- V transpose: qkv v-section -> vt[b][hkv][d][s] ----------------
__global__ __launch_bounds__(256) void v_transpose(const u16* __restrict__ qkv, u16* __restrict__ vt) {
  __shared__ __align__(16) u16 tile[64][136];
  const int blk = blockIdx.x;
  const int st = blk & 31, h = (blk >> 5) & 7, b = blk >> 8;
  const int s0 = st * 64, t = threadIdx.x;
#pragma unroll
  for (int p = 0; p < 4; ++p) {
    int row = p * 16 + (t >> 4), c8 = (t & 15) * 8;
    const u16* src = qkv + (size_t)(b * 2048 + s0 + row) * 4096 + 3072 + h * 128 + c8;
    *(short8*)&tile[row][c8] = *(const short8*)src;
  }
  __syncthreads();
  const int d = t >> 1, j0 = (t & 1) * 32;
  u16* dst = vt + ((size_t)(b * 8 + h) * 128 + d) * 2048 + s0 + j0;
#pragma unroll
  for (int j = 0; j < 32; j += 8) {
    short8 v;
#pragma unroll
    for (int u = 0; u < 8; ++u) v[u] = (short)tile[j0 + j + u][d];
    *(short8*)(dst + j) = v;
  }
}

// ---------------- causal flash attention v8: 64 q-rows per wave (2x register reuse) -------
// 2 waves/block (128 thr), 128 q/block; each LDS kf/vf read feeds TWO MFMAs (q-groups) ->
// LDS-read pipe per unit work halves vs attn7 (the measured bottleneck). Same 512-block
// complementary pairing, dbuf XOR-swizzled LDS, swapped QK^T/PV, permlane repack.
// VGPR ~370 peak -> launch_bounds(128,1), 1 wave/SIMD, 2 blocks/CU (LDS 64KB each).
__global__ __launch_bounds__(128, 1) void attn8(const u16* __restrict__ qr, const u16* __restrict__ kr,
                                                const u16* __restrict__ vt, u16* __restrict__ ao) {
  __shared__ __align__(16) u16 Ks[2][64 * 128];
  __shared__ __align__(16) u16 Vs[2][128 * 64];
  const int tid = threadIdx.x, wave = tid >> 6, lane = tid & 63;
  const int ql = lane & 31, lh = lane >> 5;

  const int blk = blockIdx.x;
  const int half = blk >> 8;                 // 0: big tiles, 1: complementary small tiles
  const int xcd = blk & 7;
  const int idx = (blk >> 3) & 31;
  const int bh = xcd * 4 + (idx & 3);
  const int pp = idx >> 2;                   // 0..7
  const int t = half ? pp : 15 - pp;
  const int b = bh >> 4, h = bh & 15, hkv = h >> 1;

  const u16* Q  = qr + (size_t)(b * 16 + h) * S_ * HD;
  const u16* Kg = kr + (size_t)(b * 8 + hkv) * S_ * HD;
  const u16* Vg = vt + (size_t)(b * 8 + hkv) * HD * S_;

  const int q0w = t * 128 + wave * 64;       // 64 q-rows per wave
  const int nsteps = 2 * (t + 1);

  short8 qf[8][2];
#pragma unroll
  for (int ki = 0; ki < 8; ++ki)
#pragma unroll
    for (int qg = 0; qg < 2; ++qg)
      qf[ki][qg] = *(const short8*)(Q + (size_t)(q0w + qg * 32 + ql) * HD + ki * 16 + lh * 8);

  f32x16 o[4][2];
#pragma unroll
  for (int dt = 0; dt < 4; ++dt) { o[dt][0] = 0.f; o[dt][1] = 0.f; }
  float m[2] = {-1e30f, -1e30f}, l[2] = {0.f, 0.f};

  auto stage = [&](int buf, int kv0) {
#pragma unroll
    for (int inst = 0; inst < 8; ++inst) {
      int p = inst * 2048 + wave * 1024 + lane * 16;   // byte pos in 16KB K tile
      int row = p >> 8;                                // kv row (256B rows)
      int colb = (p & 255) ^ ((row & 7) << 4);         // inverse swizzle on SOURCE
      load_lds16(Kg + (((size_t)(kv0 + row)) << 7) + (colb >> 1),
                 &Ks[buf][(inst * 2048 + wave * 1024) >> 1]);
    }
#pragma unroll
    for (int inst = 0; inst < 8; ++inst) {
      int p = inst * 2048 + wave * 1024 + lane * 16;   // byte pos in 16KB V tile
      int d = p >> 7;                                  // d row (128B rows)
      int colb = (p & 127) ^ ((d & 7) << 4);
      load_lds16(Vg + (size_t)d * S_ + kv0 + (colb >> 1),
                 &Vs[buf][(inst * 2048 + wave * 1024) >> 1]);
    }
  };

  stage(0, 0);
  for (int i = 0; i < nsteps; ++i) {
    const int kv0 = i * 64;
    const u16* kb = Ks[i & 1];
    const u16* vb = Vs[i & 1];
    if (i + 1 < nsteps) {
      stage((i + 1) & 1, kv0 + 64);
      ASM_VMCNT(16);                         // current buffers landed; next stays in flight
    } else {
      ASM_VMCNT(0);
    }
    __builtin_amdgcn_s_barrier();
    MEMFENCE;                                // loads can't hoist above the barrier

    if (kv0 < q0w + 64) {                    // wave-uniform: not fully masked
      f32x16 sacc[2][2];
      sacc[0][0] = 0.f; sacc[0][1] = 0.f; sacc[1][0] = 0.f; sacc[1][1] = 0.f;
      __builtin_amdgcn_s_setprio(1);
#pragma unroll
      for (int ki = 0; ki < 8; ++ki) {
        const int off = ki * 32 + lh * 16;
#pragma unroll
        for (int kvt = 0; kvt < 2; ++kvt) {
          const int row = kvt * 32 + ql;
          short8 kf = *(const short8*)&kb[(row << 7) + ((off ^ ((row & 7) << 4)) >> 1)];
          sacc[kvt][0] = __builtin_amdgcn_mfma_f32_32x32x16_bf16(kf, qf[ki][0], sacc[kvt][0], 0, 0, 0);
          sacc[kvt][1] = __builtin_amdgcn_mfma_f32_32x32x16_bf16(kf, qf[ki][1], sacc[kvt][1], 0, 0, 0);
        }
      }
      __builtin_amdgcn_s_setprio(0);
      if (kv0 + 64 > q0w) {                  // diagonal: apply causal mask
#pragma unroll
        for (int qg = 0; qg < 2; ++qg) {
          const int q = q0w + qg * 32 + ql;
#pragma unroll
          for (int kvt = 0; kvt < 2; ++kvt) {
            const int kvb = kv0 + kvt * 32 + 4 * lh;
#pragma unroll
            for (int reg = 0; reg < 16; ++reg) {
              const int kvr = kvb + (reg & 3) + 8 * (reg >> 2);
              sacc[kvt][qg][reg] = (kvr > q) ? -1e30f : sacc[kvt][qg][reg];
            }
          }
        }
      }
      float mx[2];
#pragma unroll
      for (int qg = 0; qg < 2; ++qg) {
        float v = sacc[0][qg][0];
#pragma unroll
        for (int kvt = 0; kvt < 2; ++kvt)
#pragma unroll
          for (int reg = 0; reg < 16; ++reg) v = fmaxf(v, sacc[kvt][qg][reg]);
        v = fmaxf(v, __shfl_xor(v, 32, 64));
        mx[qg] = v;
      }
      bool need = (mx[0] > m[0] + RTHR) || (mx[1] > m[1] + RTHR);
      if (__any(need)) {
#pragma unroll
        for (int qg = 0; qg < 2; ++qg) {
          float mn = fmaxf(m[qg], mx[qg]);
          float sc = exp2f_fast((m[qg] - mn) * CEXP);
          l[qg] *= sc;
          m[qg] = mn;
#pragma unroll
          for (int dt = 0; dt < 4; ++dt)
#pragma unroll
            for (int reg = 0; reg < 16; ++reg) o[dt][qg][reg] *= sc;
        }
      }
      short8 pf[4][2];
#pragma unroll
      for (int qg = 0; qg < 2; ++qg) {
        const float mc = m[qg] * CEXP;
        float ps = 0.f;
#pragma unroll
        for (int kvt = 0; kvt < 2; ++kvt) {
          float pv[16];
#pragma unroll
          for (int reg = 0; reg < 16; ++reg) {
            pv[reg] = exp2f_fast(__builtin_fmaf(sacc[kvt][qg][reg], CEXP, -mc));
            ps += pv[reg];
          }
          int A0 = cvtpk(pv[0], pv[1]),  B0 = cvtpk(pv[2], pv[3]);
          int C0 = cvtpk(pv[4], pv[5]),  D0 = cvtpk(pv[6], pv[7]);
          int A1 = cvtpk(pv[8], pv[9]),  B1 = cvtpk(pv[10], pv[11]);
          int C1 = cvtpk(pv[12], pv[13]), D1 = cvtpk(pv[14], pv[15]);
          pl32swap(A0, C0);
          pl32swap(B0, D0);
          pl32swap(A1, C1);
          pl32swap(B1, D1);
          i32x4 w0 = (i32x4){A0, B0, C0, D0};
          i32x4 w1 = (i32x4){A1, B1, C1, D1};
          pf[kvt * 2][qg]     = *(short8*)&w0;
          pf[kvt * 2 + 1][qg] = *(short8*)&w1;
        }
        l[qg] += ps;
      }
      __builtin_amdgcn_s_setprio(1);
#pragma unroll
      for (int kc = 0; kc < 4; ++kc) {
        const int off = kc * 32 + lh * 16;
#pragma unroll
        for (int dt = 0; dt < 4; ++dt) {
          const int d = dt * 32 + ql;
          short8 vf = *(const short8*)&vb[(d << 6) + ((off ^ ((d & 7) << 4)) >> 1)];
          o[dt][0] = __builtin_amdgcn_mfma_f32_32x32x16_bf16(vf, pf[kc][0], o[dt][0], 0, 0, 0);
          o[dt][1] = __builtin_amdgcn_mfma_f32_32x32x16_bf16(vf, pf[kc][1], o[dt][1], 0, 0, 0);
        }
      }
      __builtin_amdgcn_s_setprio(0);
    }
    MEMFENCE;                                // loads can't sink below the barrier
    __builtin_amdgcn_s_barrier();            // buffer consumed; next iter may overwrite
  }

#pragma unroll
  for (int qg = 0; qg < 2; ++qg) {
    float lt = l[qg];
    lt += __shfl_xor(lt, 32, 64);
    const float inv = 1.0f / lt;
    const size_t rowoff = ((size_t)(b * 2048 + q0w + qg * 32 + ql)) * 2048 + h * 128;
#pragma unroll
    for (int dt = 0; dt < 4; ++dt)
#pragma unroll
      for (int g = 0; g < 4; ++g) {
        const int d0 = dt * 32 + 8 * g + 4 * lh;
        int w0 = cvtpk(o[dt][qg][4 * g] * inv, o[dt][qg][4 * g + 1] * inv);
        int w1 = cvtpk(o[dt][qg][4 * g + 2] * inv, o[dt][qg][4 * g + 3] * inv);
        i32x2 pk = (i32x2){w0, w1};
        *(i32x2*)((u16*)ao + rowoff + d0) = pk;
      }
  }
}

extern "C" void kernel_launch(void* const* d_in, const int* in_sizes, int n_in,
                              void* d_out, int out_size, void* d_ws, size_t ws_size,
                              hipStream_t stream) {
  const float* x = (const float*)d_in[0];
  const float* fc = (const float*)d_in[1];
  const float* wq = (const float*)d_in[2];
  const float* wk = (const float*)d_in[3];
  const float* wv = (const float*)d_in[4];
  const float* wo = (const float*)d_in[5];
  const float* qw = (const float*)d_in[6];
  const float* kw = (const float*)d_in[7];
  float* out = (float*)d_out;
  char* ws = (char*)d_ws;

  u16* xb    = (u16*)(ws);                 // [4096][2048] bf16   16 MB
  u16* wqkvb = (u16*)(ws + 16777216);      // [4096][2048] bf16   16 MB
  u16* wob   = (u16*)(ws + 33554432);      // [2048][2048] bf16    8 MB
  u16* qkv   = (u16*)(ws + 41943040);      // [4096][4096] bf16   32 MB
  u16* qrope = (u16*)(ws + 75497472);      // [2][16][2048][128]  16 MB
  u16* krope = (u16*)(ws + 92274688);      // [2][8][2048][128]    8 MB
  u16* vtb   = (u16*)(ws + 100663296);     // [2][8][128][2048]    8 MB
  u16* ao    = (u16*)(ws + 109051904);     // [4096][2048] bf16   16 MB

  cvt_all<<<20480, 256, 0, stream>>>(x, wq, wk, wv, wo, xb, wqkvb, wob);

  gemm256x128<<<512, 512, 0, stream>>>(xb, wqkvb, qkv);

  rmsnorm_rope<<<24576, 256, 0, stream>>>(qkv, fc, qw, kw, qrope, krope);
  v_transpose<<<512, 256, 0, stream>>>(qkv, vtb);

  attn8<<<512, 128, 0, stream>>>(qrope, krope, vtb, ao);

  gemm_bt2<1><<<512, 256, 0, stream>>>(ao, wob, (void*)out, 4096, 2048, 2048, 16);
}

// Round 14
// 209.506 us; speedup vs baseline: 1.1851x; 1.1851x over previous
//
#include <hip/hip_runtime.h>

#define B_ 2
#define S_ 2048
#define D_ 2048
#define NH 16
#define NKV 8
#define HD 128
#define SCALE 0.08838834764831845f
#define CEXP 0.1275255f          // SCALE * log2(e)
#define RTHR 62.733f             // 8 / CEXP  (defer-max threshold, p <= 2^8)

typedef unsigned short u16;
typedef __attribute__((ext_vector_type(8))) short short8;
typedef __attribute__((ext_vector_type(4))) float f32x4;
typedef __attribute__((ext_vector_type(16))) float f32x16;
typedef __attribute__((ext_vector_type(4))) int i32x4;
typedef __attribute__((ext_vector_type(2))) int i32x2;

#define ASM_VMCNT(N) asm volatile("s_waitcnt vmcnt(" #N ")" ::: "memory")
#define MEMFENCE asm volatile("" ::: "memory")

__device__ __forceinline__ u16 f2b(float f) {
  union { float f; unsigned u; } c; c.f = f;
  unsigned u = c.u;
  return (u16)((u + 0x7fffu + ((u >> 16) & 1u)) >> 16);
}
__device__ __forceinline__ float b2f(u16 h) {
  union { unsigned u; float f; } c; c.u = ((unsigned)h) << 16;
  return c.f;
}
__device__ __forceinline__ float exp2f_fast(float x) {
  float r; asm("v_exp_f32 %0, %1" : "=v"(r) : "v"(x)); return r;
}
__device__ __forceinline__ int cvtpk(float a, float b) {  // low16=bf16(a), high16=bf16(b)
  int r; asm("v_cvt_pk_bf16_f32 %0, %1, %2" : "=v"(r) : "v"(a), "v"(b)); return r;
}
// swap: a.hi32lanes <-> b.lo32lanes (both regs updated)
__device__ __forceinline__ void pl32swap(int& a, int& b) {
  asm volatile("v_permlane32_swap_b32 %0, %1" : "+v"(a), "+v"(b));
}

__device__ __forceinline__ void load_lds16(const u16* g, u16* l) {
  __builtin_amdgcn_global_load_lds(
      (const __attribute__((address_space(1))) unsigned int*)g,
      (__attribute__((address_space(3))) unsigned int*)l, 16, 0, 0);
}

// ---------------- fused f32 -> bf16 conversion (all 5 tensors, 1 launch) ----------------
__global__ __launch_bounds__(256) void cvt_all(const float* __restrict__ x,
                                               const float* __restrict__ wq,
                                               const float* __restrict__ wk,
                                               const float* __restrict__ wv,
                                               const float* __restrict__ wo,
                                               u16* __restrict__ xb,
                                               u16* __restrict__ wqkvb,
                                               u16* __restrict__ wob) {
  const int blk = blockIdx.x;
  const float* src; u16* dst; int base;
  if (blk < 8192)       { src = x;  dst = xb;                  base = blk; }
  else if (blk < 12288) { src = wq; dst = wqkvb;               base = blk - 8192; }
  else if (blk < 14336) { src = wk; dst = wqkvb + 2048 * 2048; base = blk - 12288; }
  else if (blk < 16384) { src = wv; dst = wqkvb + 3072 * 2048; base = blk - 14336; }
  else                  { src = wo; dst = wob;                 base = blk - 16384; }
  int i = base * 256 + threadIdx.x;
  float4 v = ((const float4*)src)[i];
  u16 o0 = f2b(v.x), o1 = f2b(v.y), o2 = f2b(v.z), o3 = f2b(v.w);
  unsigned long long packed = (unsigned long long)o0 | ((unsigned long long)o1 << 16) |
                              ((unsigned long long)o2 << 32) | ((unsigned long long)o3 << 48);
  ((unsigned long long*)dst)[i] = packed;
}

// ---------------- QKV GEMM: 256x128 tile, 8 waves (4Mx2N), single-buffer LDS, 2 blocks/CU --
#define LDA4Q(dst, SRC) \
  { _Pragma("unroll") for (int i2 = 0; i2 < 4; ++i2) { \
      const int arow = wr * 64 + i2 * 16 + r; \
      dst[i2] = *(const short8*)&(SRC)[arow * 32 + ((hi ^ ((arow >> 1) & 3)) << 3)]; } }
#define LDB4Q(dst, SRC) \
  { _Pragma("unroll") for (int n2 = 0; n2 < 4; ++n2) { \
      const int brow = wc * 64 + n2 * 16 + r; \
      dst[n2] = *(const short8*)&(SRC)[brow * 32 + ((hi ^ ((brow >> 1) & 3)) << 3)]; } }
#define MFMA16Q(AF, BF) \
  { __builtin_amdgcn_s_setprio(1); \
    _Pragma("unroll") for (int i2 = 0; i2 < 4; ++i2) \
    _Pragma("unroll") for (int n2 = 0; n2 < 4; ++n2) \
      acc[i2][n2] = __builtin_amdgcn_mfma_f32_16x16x32_bf16(AF[i2], BF[n2], acc[i2][n2], 0, 0, 0); \
    __builtin_amdgcn_s_setprio(0); }

__global__ __launch_bounds__(512, 4) void gemm256x128(const u16* __restrict__ A,
                                                      const u16* __restrict__ Bm,
                                                      u16* __restrict__ C) {
  __shared__ __align__(16) u16 As2[2][8192];   // [kc][256 rows x 32 k]  32 KB
  __shared__ __align__(16) u16 Bs2[2][4096];   // [kc][128 rows x 32 k]  16 KB
  const int tid = threadIdx.x;
  const int wave = tid >> 6, lane = tid & 63;
  const int L = (blockIdx.x & 7) * 64 + (blockIdx.x >> 3);  // bijective XCD chunking
  const int bm = L >> 5, bn = L & 31;          // 16 x 32 tile grid
  const int wr = wave >> 1, wc = wave & 1;     // 4M x 2N waves; per-wave 64x64
  const int r = lane & 15, hi = lane >> 4;
  const int rowA0 = bm * 256, rowB0 = bn * 128;

  f32x4 acc[4][4];
#pragma unroll
  for (int mi = 0; mi < 4; ++mi)
#pragma unroll
    for (int ni = 0; ni < 4; ++ni) acc[mi][ni] = (f32x4){0.f, 0.f, 0.f, 0.f};

  auto stage_ha = [&](u16* lds, int kcol) {
#pragma unroll
    for (int l = 0; l < 2; ++l) {
      const int p = wave * 2048 + l * 1024 + lane * 16;
      const int row = p >> 6, slot = (p >> 4) & 3;
      const int kg = slot ^ ((row >> 1) & 3);
      load_lds16(A + (size_t)(rowA0 + row) * 2048 + kcol + kg * 8,
                 lds + ((wave * 2048 + l * 1024) >> 1));
    }
  };
  auto stage_hb = [&](u16* lds, int kcol) {
    const int p = wave * 1024 + lane * 16;
    const int row = p >> 6, slot = (p >> 4) & 3;
    const int kg = slot ^ ((row >> 1) & 3);
    load_lds16(Bm + (size_t)(rowB0 + row) * 2048 + kcol + kg * 8,
               lds + ((wave * 1024) >> 1));
  };

  for (int kt = 0; kt < 32; ++kt) {
    const int k0 = kt << 6;
    stage_ha(As2[0], k0);
    stage_hb(Bs2[0], k0);
    stage_ha(As2[1], k0 + 32);
    stage_hb(Bs2[1], k0 + 32);
    ASM_VMCNT(0);
    __builtin_amdgcn_s_barrier();
    MEMFENCE;
    short8 af[4], bf[4];
    LDB4Q(bf, Bs2[0]); LDA4Q(af, As2[0]);
    MFMA16Q(af, bf);
    LDB4Q(bf, Bs2[1]); LDA4Q(af, As2[1]);
    MFMA16Q(af, bf);
    MEMFENCE;
    __builtin_amdgcn_s_barrier();   // all reads done before next stage overwrites
  }

#pragma unroll
  for (int mi = 0; mi < 4; ++mi)
#pragma unroll
    for (int ni = 0; ni < 4; ++ni)
#pragma unroll
      for (int r2 = 0; r2 < 4; ++r2) {
        int grow = bm * 256 + wr * 64 + mi * 16 + hi * 4 + r2;
        int gcol = bn * 128 + wc * 64 + ni * 16 + r;
        C[(size_t)grow * 4096 + gcol] = f2b(acc[mi][ni][r2]);
      }
}

// ---------------- out-GEMM (128^2): single-buffer LDS, 4 blocks/CU co-resident ----------
// R12 lesson: co-residency (not intra-block pipelining) covers the stage/vmcnt/barrier
// stalls. Single 32KB buffer -> launch_bounds(256,4): all 512 blocks resident (4/CU cap,
// 16 waves x 88 VGPR = 1408 <= 2048 pool, 128KB LDS).
template<int OUTF32>
__global__ __launch_bounds__(256, 4) void gemm_bt3(const u16* __restrict__ A, const u16* __restrict__ Bm,
                                                   void* __restrict__ Cv, int M, int N, int K, int nbn) {
  __shared__ __align__(16) u16 As[128 * 64];   // 16 KB
  __shared__ __align__(16) u16 Bs[128 * 64];   // 16 KB
  const int tid = threadIdx.x;
  const int wave = tid >> 6, lane = tid & 63;
  const int nwg = gridDim.x, cpx = nwg >> 3;
  const int L = (blockIdx.x & 7) * cpx + (blockIdx.x >> 3);
  const int bm = L / nbn, bn = L % nbn;
  const int wr = wave >> 1, wc = wave & 1;
  const int r = lane & 15, hi = lane >> 4;

  f32x4 acc[4][4];
#pragma unroll
  for (int m = 0; m < 4; ++m)
#pragma unroll
    for (int n = 0; n < 4; ++n) acc[m][n] = (f32x4){0.f, 0.f, 0.f, 0.f};

  const int gslot = (lane & 7) ^ (lane >> 3);
  const int srow = lane >> 3;

  auto stage = [&](int k0) {
#pragma unroll
    for (int jj = 0; jj < 4; ++jj) {
      int j = wave * 4 + jj;
      int row = j * 8 + srow;
      load_lds16(A + (size_t)(bm * 128 + row) * K + k0 + gslot * 8, &As[j * 512]);
      load_lds16(Bm + (size_t)(bn * 128 + row) * K + k0 + gslot * 8, &Bs[j * 512]);
    }
  };

  const int nk = K >> 6;
  for (int kt = 0; kt < nk; ++kt) {
    stage(kt << 6);
    ASM_VMCNT(0);
    __builtin_amdgcn_s_barrier();
    MEMFENCE;
#pragma unroll
    for (int kc = 0; kc < 2; ++kc) {
      short8 af[4], bfr[4];
#pragma unroll
      for (int m = 0; m < 4; ++m) {
        int row = wr * 64 + m * 16 + r;
        int slot = (hi + kc * 4) ^ (row & 7);
        af[m] = *(const short8*)&As[row * 64 + slot * 8];
      }
#pragma unroll
      for (int n = 0; n < 4; ++n) {
        int row = wc * 64 + n * 16 + r;
        int slot = (hi + kc * 4) ^ (row & 7);
        bfr[n] = *(const short8*)&Bs[row * 64 + slot * 8];
      }
#pragma unroll
      for (int m = 0; m < 4; ++m)
#pragma unroll
        for (int n = 0; n < 4; ++n)
          acc[m][n] = __builtin_amdgcn_mfma_f32_16x16x32_bf16(af[m], bfr[n], acc[m][n], 0, 0, 0);
    }
    MEMFENCE;
    __builtin_amdgcn_s_barrier();   // reads done before next stage overwrites
  }

#pragma unroll
  for (int m = 0; m < 4; ++m)
#pragma unroll
    for (int n = 0; n < 4; ++n)
#pragma unroll
      for (int r2 = 0; r2 < 4; ++r2) {
        int grow = bm * 128 + wr * 64 + m * 16 + hi * 4 + r2;
        int gcol = bn * 128 + wc * 64 + n * 16 + r;
        if (OUTF32)
          ((float*)Cv)[(size_t)grow * N + gcol] = acc[m][n][r2];
        else
          ((u16*)Cv)[(size_t)grow * N + gcol] = f2b(acc[m][n][r2]);
      }
}

// ---------------- per-head RMSNorm + RoPE for Q and K ----------------
__global__ __launch_bounds__(256) void rmsnorm_rope(const u16* __restrict__ qkv, const float* __restrict__ fc,
                                                    const float* __restrict__ qw, const float* __restrict__ kw,
                                                    u16* __restrict__ qr, u16* __restrict__ kr) {
  const int tid = threadIdx.x, wave = tid >> 6, lane = tid & 63;
  const int rowid = blockIdx.x * 4 + wave;
  const int token = rowid / 24;
  const int hh = rowid % 24;
  const int b = token >> 11, s = token & 2047;
  const bool isq = hh < 16;
  const int off = isq ? hh * 128 : 2048 + (hh - 16) * 128;
  const u16* src = qkv + (size_t)token * 4096 + off + lane * 2;
  unsigned pv = *(const unsigned*)src;
  float t0 = b2f((u16)(pv & 0xffffu));
  float t1 = b2f((u16)(pv >> 16));
  float ss = t0 * t0 + t1 * t1;
#pragma unroll
  for (int mm = 1; mm < 64; mm <<= 1) ss += __shfl_xor(ss, mm, 64);
  float rms = rsqrtf(ss * (1.0f / 128.0f) + 1e-6f);
  const float* nw = isq ? qw : kw;
  t0 *= rms * nw[lane * 2];
  t1 *= rms * nw[lane * 2 + 1];
  float c = fc[(s * 64 + lane) * 2], sn = fc[(s * 64 + lane) * 2 + 1];
  float o0 = t0 * c - t1 * sn;
  float o1 = t0 * sn + t1 * c;
  unsigned ov = (unsigned)f2b(o0) | ((unsigned)f2b(o1) << 16);
  if (isq)
    *(unsigned*)(qr + ((size_t)(b * 16 + hh) * 2048 + s) * 128 + lane * 2) = ov;
  else
    *(unsigned*)(kr + ((size_t)(b * 8 + hh - 16) * 2048 + s) * 128 + lane * 2) = ov;
}

// ---------------- V transpose: qkv v-section -> vt[b][hkv][d][s] ----------------
__global__ __launch_bounds__(256) void v_transpose(const u16* __restrict__ qkv, u16* __restrict__ vt) {
  __shared__ __align__(16) u16 tile[64][136];
  const int blk = blockIdx.x;
  const int st = blk & 31, h = (blk >> 5) & 7, b = blk >> 8;
  const int s0 = st * 64, t = threadIdx.x;
#pragma unroll
  for (int p = 0; p < 4; ++p) {
    int row = p * 16 + (t >> 4), c8 = (t & 15) * 8;
    const u16* src = qkv + (size_t)(b * 2048 + s0 + row) * 4096 + 3072 + h * 128 + c8;
    *(short8*)&tile[row][c8] = *(const short8*)src;
  }
  __syncthreads();
  const int d = t >> 1, j0 = (t & 1) * 32;
  u16* dst = vt + ((size_t)(b * 8 + h) * 128 + d) * 2048 + s0 + j0;
#pragma unroll
  for (int j = 0; j < 32; j += 8) {
    short8 v;
#pragma unroll
    for (int u = 0; u < 8; ++u) v[u] = (short)tile[j0 + j + u][d];
    *(short8*)(dst + j) = v;
  }
}

// ---------------- causal flash attention v7: one tile/block, complementary pairing ----------------
__global__ __launch_bounds__(256, 2) void attn7(const u16* __restrict__ qr, const u16* __restrict__ kr,
                                                const u16* __restrict__ vt, u16* __restrict__ ao) {
  __shared__ __align__(16) u16 Ks[2][64 * 128];
  __shared__ __align__(16) u16 Vs[2][128 * 64];
  const int tid = threadIdx.x, wave = tid >> 6, lane = tid & 63;
  const int ql = lane & 31, lh = lane >> 5;

  const int blk = blockIdx.x;
  const int half = blk >> 8;                 // 0: big tiles, 1: complementary small tiles
  const int xcd = blk & 7;
  const int idx = (blk >> 3) & 31;
  const int bh = xcd * 4 + (idx & 3);
  const int pp = idx >> 2;                   // 0..7
  const int t = half ? pp : 15 - pp;
  const int b = bh >> 4, h = bh & 15, hkv = h >> 1;

  const u16* Q  = qr + (size_t)(b * 16 + h) * S_ * HD;
  const u16* Kg = kr + (size_t)(b * 8 + hkv) * S_ * HD;
  const u16* Vg = vt + (size_t)(b * 8 + hkv) * HD * S_;

  const int q0w = t * 128 + wave * 32;
  const int nsteps = 2 * (t + 1);

  short8 qf[8];
#pragma unroll
  for (int ki = 0; ki < 8; ++ki)
    qf[ki] = *(const short8*)(Q + (size_t)(q0w + ql) * HD + ki * 16 + lh * 8);

  f32x16 o[4];
#pragma unroll
  for (int dt = 0; dt < 4; ++dt) o[dt] = 0.f;
  float m = -1e30f, l = 0.f;

  auto stage = [&](int buf, int kv0) {
#pragma unroll
    for (int inst = 0; inst < 4; ++inst) {
      int pp2 = wave * 4096 + inst * 1024 + lane * 16;
      int row = pp2 >> 8;
      int colb = (pp2 & 255) ^ ((row & 7) << 4);
      load_lds16(Kg + (((size_t)(kv0 + row)) << 7) + (colb >> 1),
                 &Ks[buf][(wave * 4096 + inst * 1024) >> 1]);
    }
#pragma unroll
    for (int inst = 0; inst < 4; ++inst) {
      int pp2 = wave * 4096 + inst * 1024 + lane * 16;
      int d = pp2 >> 7;
      int colb = (pp2 & 127) ^ ((d & 7) << 4);
      load_lds16(Vg + (size_t)d * S_ + kv0 + (colb >> 1),
                 &Vs[buf][(wave * 4096 + inst * 1024) >> 1]);
    }
  };

  stage(0, 0);
  for (int i = 0; i < nsteps; ++i) {
    const int kv0 = i * 64;
    const u16* kb = Ks[i & 1];
    const u16* vb = Vs[i & 1];
    if (i + 1 < nsteps) {
      stage((i + 1) & 1, kv0 + 64);
      ASM_VMCNT(8);
    } else {
      ASM_VMCNT(0);
    }
    __builtin_amdgcn_s_barrier();
    MEMFENCE;                                // loads can't hoist above the barrier

    if (kv0 < q0w + 32) {
      f32x16 sacc[2];
      sacc[0] = 0.f; sacc[1] = 0.f;
      __builtin_amdgcn_s_setprio(1);
#pragma unroll
      for (int ki = 0; ki < 8; ++ki) {
        const int off = ki * 32 + lh * 16;
#pragma unroll
        for (int kvt = 0; kvt < 2; ++kvt) {
          const int row = kvt * 32 + ql;
          short8 kf = *(const short8*)&kb[(row << 7) + ((off ^ ((row & 7) << 4)) >> 1)];
          sacc[kvt] = __builtin_amdgcn_mfma_f32_32x32x16_bf16(kf, qf[ki], sacc[kvt], 0, 0, 0);
        }
      }
      __builtin_amdgcn_s_setprio(0);
      const int q = q0w + ql;
      if (kv0 + 64 > q0w) {
#pragma unroll
        for (int kvt = 0; kvt < 2; ++kvt) {
          const int kvb = kv0 + kvt * 32 + 4 * lh;
#pragma unroll
          for (int reg = 0; reg < 16; ++reg) {
            const int kvr = kvb + (reg & 3) + 8 * (reg >> 2);
            sacc[kvt][reg] = (kvr > q) ? -1e30f : sacc[kvt][reg];
          }
        }
      }
      float mx = sacc[0][0];
#pragma unroll
      for (int kvt = 0; kvt < 2; ++kvt)
#pragma unroll
        for (int reg = 0; reg < 16; ++reg) mx = fmaxf(mx, sacc[kvt][reg]);
      mx = fmaxf(mx, __shfl_xor(mx, 32, 64));
      if (__any(mx > m + RTHR)) {
        float mn = fmaxf(m, mx);
        float sc = exp2f_fast((m - mn) * CEXP);
        l *= sc;
        m = mn;
#pragma unroll
        for (int dt = 0; dt < 4; ++dt)
#pragma unroll
          for (int reg = 0; reg < 16; ++reg) o[dt][reg] *= sc;
      }
      short8 pf[4];
      const float mc = m * CEXP;
      float ps = 0.f;
#pragma unroll
      for (int kvt = 0; kvt < 2; ++kvt) {
        float pv[16];
#pragma unroll
        for (int reg = 0; reg < 16; ++reg) {
          pv[reg] = exp2f_fast(__builtin_fmaf(sacc[kvt][reg], CEXP, -mc));
          ps += pv[reg];
        }
        int A0 = cvtpk(pv[0], pv[1]),  B0 = cvtpk(pv[2], pv[3]);
        int C0 = cvtpk(pv[4], pv[5]),  D0 = cvtpk(pv[6], pv[7]);
        int A1 = cvtpk(pv[8], pv[9]),  B1 = cvtpk(pv[10], pv[11]);
        int C1 = cvtpk(pv[12], pv[13]), D1 = cvtpk(pv[14], pv[15]);
        pl32swap(A0, C0);
        pl32swap(B0, D0);
        pl32swap(A1, C1);
        pl32swap(B1, D1);
        i32x4 w0 = (i32x4){A0, B0, C0, D0};
        i32x4 w1 = (i32x4){A1, B1, C1, D1};
        pf[kvt * 2]     = *(short8*)&w0;
        pf[kvt * 2 + 1] = *(short8*)&w1;
      }
      l += ps;
      __builtin_amdgcn_s_setprio(1);
#pragma unroll
      for (int kc = 0; kc < 4; ++kc) {
        const int off = kc * 32 + lh * 16;
#pragma unroll
        for (int dt = 0; dt < 4; ++dt) {
          const int d = dt * 32 + ql;
          short8 vf = *(const short8*)&vb[(d << 6) + ((off ^ ((d & 7) << 4)) >> 1)];
          o[dt] = __builtin_amdgcn_mfma_f32_32x32x16_bf16(vf, pf[kc], o[dt], 0, 0, 0);
        }
      }
      __builtin_amdgcn_s_setprio(0);
    }
    MEMFENCE;                                // loads can't sink below the barrier
    __builtin_amdgcn_s_barrier();            // buffer consumed; next iter may overwrite
  }

  l += __shfl_xor(l, 32, 64);
  const float inv = 1.0f / l;
  const size_t rowoff = ((size_t)(b * 2048 + q0w + ql)) * 2048 + h * 128;
#pragma unroll
  for (int dt = 0; dt < 4; ++dt)
#pragma unroll
    for (int g = 0; g < 4; ++g) {
      const int d0 = dt * 32 + 8 * g + 4 * lh;
      int w0 = cvtpk(o[dt][4 * g] * inv, o[dt][4 * g + 1] * inv);
      int w1 = cvtpk(o[dt][4 * g + 2] * inv, o[dt][4 * g + 3] * inv);
      i32x2 pk = (i32x2){w0, w1};
      *(i32x2*)((u16*)ao + rowoff + d0) = pk;
    }
}

extern "C" void kernel_launch(void* const* d_in, const int* in_sizes, int n_in,
                              void* d_out, int out_size, void* d_ws, size_t ws_size,
                              hipStream_t stream) {
  const float* x = (const float*)d_in[0];
  const float* fc = (const float*)d_in[1];
  const float* wq = (const float*)d_in[2];
  const float* wk = (const float*)d_in[3];
  const float* wv = (const float*)d_in[4];
  const float* wo = (const float*)d_in[5];
  const float* qw = (const float*)d_in[6];
  const float* kw = (const float*)d_in[7];
  float* out = (float*)d_out;
  char* ws = (char*)d_ws;

  u16* xb    = (u16*)(ws);                 // [4096][2048] bf16   16 MB
  u16* wqkvb = (u16*)(ws + 16777216);      // [4096][2048] bf16   16 MB
  u16* wob   = (u16*)(ws + 33554432);      // [2048][2048] bf16    8 MB
  u16* qkv   = (u16*)(ws + 41943040);      // [4096][4096] bf16   32 MB
  u16* qrope = (u16*)(ws + 75497472);      // [2][16][2048][128]  16 MB
  u16* krope = (u16*)(ws + 92274688);      // [2][8][2048][128]    8 MB
  u16* vtb   = (u16*)(ws + 100663296);     // [2][8][128][2048]    8 MB
  u16* ao    = (u16*)(ws + 109051904);     // [4096][2048] bf16   16 MB

  cvt_all<<<20480, 256, 0, stream>>>(x, wq, wk, wv, wo, xb, wqkvb, wob);

  gemm256x128<<<512, 512, 0, stream>>>(xb, wqkvb, qkv);

  rmsnorm_rope<<<24576, 256, 0, stream>>>(qkv, fc, qw, kw, qrope, krope);
  v_transpose<<<512, 256, 0, stream>>>(qkv, vtb);

  attn7<<<512, 256, 0, stream>>>(qrope, krope, vtb, ao);

  gemm_bt3<1><<<512, 256, 0, stream>>>(ao, wob, (void*)out, 4096, 2048, 2048, 16);
}

// Round 15
// 195.223 us; speedup vs baseline: 1.2718x; 1.0732x over previous
//
#include <hip/hip_runtime.h>

#define B_ 2
#define S_ 2048
#define D_ 2048
#define NH 16
#define NKV 8
#define HD 128
#define SCALE 0.08838834764831845f
#define CEXP 0.1275255f          // SCALE * log2(e)
#define RTHR 62.733f             // 8 / CEXP  (defer-max threshold, p <= 2^8)

typedef unsigned short u16;
typedef __attribute__((ext_vector_type(8))) short short8;
typedef __attribute__((ext_vector_type(4))) float f32x4;
typedef __attribute__((ext_vector_type(16))) float f32x16;
typedef __attribute__((ext_vector_type(4))) int i32x4;
typedef __attribute__((ext_vector_type(2))) int i32x2;

#define ASM_VMCNT(N) asm volatile("s_waitcnt vmcnt(" #N ")" ::: "memory")
#define MEMFENCE asm volatile("" ::: "memory")

__device__ __forceinline__ u16 f2b(float f) {
  union { float f; unsigned u; } c; c.f = f;
  unsigned u = c.u;
  return (u16)((u + 0x7fffu + ((u >> 16) & 1u)) >> 16);
}
__device__ __forceinline__ float b2f(u16 h) {
  union { unsigned u; float f; } c; c.u = ((unsigned)h) << 16;
  return c.f;
}
__device__ __forceinline__ float exp2f_fast(float x) {
  float r; asm("v_exp_f32 %0, %1" : "=v"(r) : "v"(x)); return r;
}
__device__ __forceinline__ int cvtpk(float a, float b) {  // low16=bf16(a), high16=bf16(b)
  int r; asm("v_cvt_pk_bf16_f32 %0, %1, %2" : "=v"(r) : "v"(a), "v"(b)); return r;
}
// swap: a.hi32lanes <-> b.lo32lanes (both regs updated)
__device__ __forceinline__ void pl32swap(int& a, int& b) {
  asm volatile("v_permlane32_swap_b32 %0, %1" : "+v"(a), "+v"(b));
}

__device__ __forceinline__ void load_lds16(const u16* g, u16* l) {
  __builtin_amdgcn_global_load_lds(
      (const __attribute__((address_space(1))) unsigned int*)g,
      (__attribute__((address_space(3))) unsigned int*)l, 16, 0, 0);
}

// ---------------- fused f32 -> bf16 conversion (all 5 tensors, 1 launch) ----------------
__global__ __launch_bounds__(256) void cvt_all(const float* __restrict__ x,
                                               const float* __restrict__ wq,
                                               const float* __restrict__ wk,
                                               const float* __restrict__ wv,
                                               const float* __restrict__ wo,
                                               u16* __restrict__ xb,
                                               u16* __restrict__ wqkvb,
                                               u16* __restrict__ wob) {
  const int blk = blockIdx.x;
  const float* src; u16* dst; int base;
  if (blk < 8192)       { src = x;  dst = xb;                  base = blk; }
  else if (blk < 12288) { src = wq; dst = wqkvb;               base = blk - 8192; }
  else if (blk < 14336) { src = wk; dst = wqkvb + 2048 * 2048; base = blk - 12288; }
  else if (blk < 16384) { src = wv; dst = wqkvb + 3072 * 2048; base = blk - 14336; }
  else                  { src = wo; dst = wob;                 base = blk - 16384; }
  int i = base * 256 + threadIdx.x;
  float4 v = ((const float4*)src)[i];
  u16 o0 = f2b(v.x), o1 = f2b(v.y), o2 = f2b(v.z), o3 = f2b(v.w);
  unsigned long long packed = (unsigned long long)o0 | ((unsigned long long)o1 << 16) |
                              ((unsigned long long)o2 << 32) | ((unsigned long long)o3 << 48);
  ((unsigned long long*)dst)[i] = packed;
}

// ---------------- QKV GEMM + fused RMSNorm/RoPE/V-transpose epilogue ----------------
// 256x128 tile, 8 waves (4Mx2N), single-buffer LDS, >=2 blocks/CU. bn tile = exactly one
// head (128 cols): bn 0-15 -> Q head bn; 16-23 -> K head bn-16; 24-31 -> V head bn-24.
// Epilogue: Q/K rows get RMSNorm (row-reduce: 4 squares + 4x shfl_xor + 2KB LDS cross-wave
// exchange) then RoPE (pairs = adjacent lanes, shfl_xor 1) and store to qrope/krope;
// V stores transposed (4-token bf16 runs, 8B) to vt. Replaces rmsnorm_rope + v_transpose.
#define LDA4Q(dst, SRC) \
  { _Pragma("unroll") for (int i2 = 0; i2 < 4; ++i2) { \
      const int arow = wr * 64 + i2 * 16 + r; \
      dst[i2] = *(const short8*)&(SRC)[arow * 32 + ((hi ^ ((arow >> 1) & 3)) << 3)]; } }
#define LDB4Q(dst, SRC) \
  { _Pragma("unroll") for (int n2 = 0; n2 < 4; ++n2) { \
      const int brow = wc * 64 + n2 * 16 + r; \
      dst[n2] = *(const short8*)&(SRC)[brow * 32 + ((hi ^ ((brow >> 1) & 3)) << 3)]; } }
#define MFMA16Q(AF, BF) \
  { __builtin_amdgcn_s_setprio(1); \
    _Pragma("unroll") for (int i2 = 0; i2 < 4; ++i2) \
    _Pragma("unroll") for (int n2 = 0; n2 < 4; ++n2) \
      acc[i2][n2] = __builtin_amdgcn_mfma_f32_16x16x32_bf16(AF[i2], BF[n2], acc[i2][n2], 0, 0, 0); \
    __builtin_amdgcn_s_setprio(0); }

__global__ __launch_bounds__(512, 4) void gemm_qkv_fused(const u16* __restrict__ A,
                                                         const u16* __restrict__ Bm,
                                                         const float* __restrict__ fc,
                                                         const float* __restrict__ qw,
                                                         const float* __restrict__ kw,
                                                         u16* __restrict__ qrope,
                                                         u16* __restrict__ krope,
                                                         u16* __restrict__ vt) {
  __shared__ __align__(16) u16 As2[2][8192];   // [kc][256 rows x 32 k]  32 KB
  __shared__ __align__(16) u16 Bs2[2][4096];   // [kc][128 rows x 32 k]  16 KB
  __shared__ float sq[2][256];                 // cross-wave sumsq exchange  2 KB
  const int tid = threadIdx.x;
  const int wave = tid >> 6, lane = tid & 63;
  const int L = (blockIdx.x & 7) * 64 + (blockIdx.x >> 3);  // bijective XCD chunking
  const int bm = L >> 5, bn = L & 31;          // 16 x 32 tile grid
  const int wr = wave >> 1, wc = wave & 1;     // 4M x 2N waves; per-wave 64x64
  const int r = lane & 15, hi = lane >> 4;
  const int rowA0 = bm * 256, rowB0 = bn * 128;

  f32x4 acc[4][4];
#pragma unroll
  for (int mi = 0; mi < 4; ++mi)
#pragma unroll
    for (int ni = 0; ni < 4; ++ni) acc[mi][ni] = (f32x4){0.f, 0.f, 0.f, 0.f};

  auto stage_ha = [&](u16* lds, int kcol) {
#pragma unroll
    for (int l = 0; l < 2; ++l) {
      const int p = wave * 2048 + l * 1024 + lane * 16;
      const int row = p >> 6, slot = (p >> 4) & 3;
      const int kg = slot ^ ((row >> 1) & 3);
      load_lds16(A + (size_t)(rowA0 + row) * 2048 + kcol + kg * 8,
                 lds + ((wave * 2048 + l * 1024) >> 1));
    }
  };
  auto stage_hb = [&](u16* lds, int kcol) {
    const int p = wave * 1024 + lane * 16;
    const int row = p >> 6, slot = (p >> 4) & 3;
    const int kg = slot ^ ((row >> 1) & 3);
    load_lds16(Bm + (size_t)(rowB0 + row) * 2048 + kcol + kg * 8,
               lds + ((wave * 1024) >> 1));
  };

  for (int kt = 0; kt < 32; ++kt) {
    const int k0 = kt << 6;
    stage_ha(As2[0], k0);
    stage_hb(Bs2[0], k0);
    stage_ha(As2[1], k0 + 32);
    stage_hb(Bs2[1], k0 + 32);
    ASM_VMCNT(0);
    __builtin_amdgcn_s_barrier();
    MEMFENCE;
    short8 af[4], bf[4];
    LDB4Q(bf, Bs2[0]); LDA4Q(af, As2[0]);
    MFMA16Q(af, bf);
    LDB4Q(bf, Bs2[1]); LDA4Q(af, As2[1]);
    MFMA16Q(af, bf);
    MEMFENCE;
    __builtin_amdgcn_s_barrier();   // all reads done before next stage overwrites
  }

  // ---- fused epilogue ----
  if (bn >= 24) {
    // V head: no norm/rope; store transposed vt[(b*8+hv)*128+d][s]
    const int hv = bn - 24;
#pragma unroll
    for (int mi = 0; mi < 4; ++mi) {
      const int tok0 = bm * 256 + wr * 64 + mi * 16 + hi * 4;
      const int bb = tok0 >> 11, sl = tok0 & 2047;
#pragma unroll
      for (int ni = 0; ni < 4; ++ni) {
        const int d = wc * 64 + ni * 16 + r;
        int w0 = cvtpk(acc[mi][ni][0], acc[mi][ni][1]);
        int w1 = cvtpk(acc[mi][ni][2], acc[mi][ni][3]);
        i32x2 pk = (i32x2){w0, w1};
        *(i32x2*)(vt + ((size_t)(bb * 8 + hv) * 128 + d) * 2048 + sl) = pk;
      }
    }
  } else {
    // Q/K head: RMSNorm over the 128-col row, then RoPE, then store.
    const float* nw = (bn < 16) ? qw : kw;
    float nwv[4];
#pragma unroll
    for (int ni = 0; ni < 4; ++ni) nwv[ni] = nw[wc * 64 + ni * 16 + r];
    // lane-local sumsq over this wave's 64 cols, reduced across the 16 r-lanes
    float ssq[4][4];
#pragma unroll
    for (int mi = 0; mi < 4; ++mi)
#pragma unroll
      for (int r2 = 0; r2 < 4; ++r2) {
        float s4 = 0.f;
#pragma unroll
        for (int ni = 0; ni < 4; ++ni) {
          float a = acc[mi][ni][r2];
          s4 = __builtin_fmaf(a, a, s4);
        }
#pragma unroll
        for (int mk = 1; mk < 16; mk <<= 1) s4 += __shfl_xor(s4, mk, 64);
        ssq[mi][r2] = s4;
      }
    if (r == 0) {
#pragma unroll
      for (int mi = 0; mi < 4; ++mi)
#pragma unroll
        for (int r2 = 0; r2 < 4; ++r2)
          sq[wc][wr * 64 + mi * 16 + hi * 4 + r2] = ssq[mi][r2];
    }
    __syncthreads();   // block-uniform branch (bn uniform) -> safe
    u16* outp = (bn < 16) ? qrope : krope;
#pragma unroll
    for (int mi = 0; mi < 4; ++mi) {
      const int tok0 = bm * 256 + wr * 64 + mi * 16 + hi * 4;
      const int bb = tok0 >> 11;
      const size_t headbase = (bn < 16) ? ((size_t)(bb * 16 + bn) * 2048)
                                        : ((size_t)(bb * 8 + (bn - 16)) * 2048);
#pragma unroll
      for (int r2 = 0; r2 < 4; ++r2) {
        const int sl = (tok0 + r2) & 2047;
        const float tot = ssq[mi][r2] + sq[wc ^ 1][wr * 64 + mi * 16 + hi * 4 + r2];
        const float rms = rsqrtf(tot * (1.0f / 128.0f) + 1e-6f);
#pragma unroll
        for (int ni = 0; ni < 4; ++ni) {
          const int d = wc * 64 + ni * 16 + r;
          float val = acc[mi][ni][r2] * rms * nwv[ni];
          float prt = __shfl_xor(val, 1, 64);
          const float2 cs = *(const float2*)&fc[(size_t)(sl * 64 + (d >> 1)) * 2];
          float outv = (r & 1) ? (prt * cs.y + val * cs.x)     // odd col: tr*sin + ti*cos
                               : (val * cs.x - prt * cs.y);    // even col: tr*cos - ti*sin
          outp[(headbase + sl) * 128 + d] = f2b(outv);
        }
      }
    }
  }
}

// ---------------- out-GEMM (128^2): single-buffer LDS, co-resident blocks ----------
template<int OUTF32>
__global__ __launch_bounds__(256, 4) void gemm_bt3(const u16* __restrict__ A, const u16* __restrict__ Bm,
                                                   void* __restrict__ Cv, int M, int N, int K, int nbn) {
  __shared__ __align__(16) u16 As[128 * 64];   // 16 KB
  __shared__ __align__(16) u16 Bs[128 * 64];   // 16 KB
  const int tid = threadIdx.x;
  const int wave = tid >> 6, lane = tid & 63;
  const int nwg = gridDim.x, cpx = nwg >> 3;
  const int L = (blockIdx.x & 7) * cpx + (blockIdx.x >> 3);
  const int bm = L / nbn, bn = L % nbn;
  const int wr = wave >> 1, wc = wave & 1;
  const int r = lane & 15, hi = lane >> 4;

  f32x4 acc[4][4];
#pragma unroll
  for (int m = 0; m < 4; ++m)
#pragma unroll
    for (int n = 0; n < 4; ++n) acc[m][n] = (f32x4){0.f, 0.f, 0.f, 0.f};

  const int gslot = (lane & 7) ^ (lane >> 3);
  const int srow = lane >> 3;

  auto stage = [&](int k0) {
#pragma unroll
    for (int jj = 0; jj < 4; ++jj) {
      int j = wave * 4 + jj;
      int row = j * 8 + srow;
      load_lds16(A + (size_t)(bm * 128 + row) * K + k0 + gslot * 8, &As[j * 512]);
      load_lds16(Bm + (size_t)(bn * 128 + row) * K + k0 + gslot * 8, &Bs[j * 512]);
    }
  };

  const int nk = K >> 6;
  for (int kt = 0; kt < nk; ++kt) {
    stage(kt << 6);
    ASM_VMCNT(0);
    __builtin_amdgcn_s_barrier();
    MEMFENCE;
#pragma unroll
    for (int kc = 0; kc < 2; ++kc) {
      short8 af[4], bfr[4];
#pragma unroll
      for (int m = 0; m < 4; ++m) {
        int row = wr * 64 + m * 16 + r;
        int slot = (hi + kc * 4) ^ (row & 7);
        af[m] = *(const short8*)&As[row * 64 + slot * 8];
      }
#pragma unroll
      for (int n = 0; n < 4; ++n) {
        int row = wc * 64 + n * 16 + r;
        int slot = (hi + kc * 4) ^ (row & 7);
        bfr[n] = *(const short8*)&Bs[row * 64 + slot * 8];
      }
#pragma unroll
      for (int m = 0; m < 4; ++m)
#pragma unroll
        for (int n = 0; n < 4; ++n)
          acc[m][n] = __builtin_amdgcn_mfma_f32_16x16x32_bf16(af[m], bfr[n], acc[m][n], 0, 0, 0);
    }
    MEMFENCE;
    __builtin_amdgcn_s_barrier();   // reads done before next stage overwrites
  }

#pragma unroll
  for (int m = 0; m < 4; ++m)
#pragma unroll
    for (int n = 0; n < 4; ++n)
#pragma unroll
      for (int r2 = 0; r2 < 4; ++r2) {
        int grow = bm * 128 + wr * 64 + m * 16 + hi * 4 + r2;
        int gcol = bn * 128 + wc * 64 + n * 16 + r;
        if (OUTF32)
          ((float*)Cv)[(size_t)grow * N + gcol] = acc[m][n][r2];
        else
          ((u16*)Cv)[(size_t)grow * N + gcol] = f2b(acc[m][n][r2]);
      }
}

// ---------------- causal flash attention v7: one tile/block, complementary pairing ----------------
__global__ __launch_bounds__(256, 2) void attn7(const u16* __restrict__ qr, const u16* __restrict__ kr,
                                                const u16* __restrict__ vt, u16* __restrict__ ao) {
  __shared__ __align__(16) u16 Ks[2][64 * 128];
  __shared__ __align__(16) u16 Vs[2][128 * 64];
  const int tid = threadIdx.x, wave = tid >> 6, lane = tid & 63;
  const int ql = lane & 31, lh = lane >> 5;

  const int blk = blockIdx.x;
  const int half = blk >> 8;                 // 0: big tiles, 1: complementary small tiles
  const int xcd = blk & 7;
  const int idx = (blk >> 3) & 31;
  const int bh = xcd * 4 + (idx & 3);
  const int pp = idx >> 2;                   // 0..7
  const int t = half ? pp : 15 - pp;
  const int b = bh >> 4, h = bh & 15, hkv = h >> 1;

  const u16* Q  = qr + (size_t)(b * 16 + h) * S_ * HD;
  const u16* Kg = kr + (size_t)(b * 8 + hkv) * S_ * HD;
  const u16* Vg = vt + (size_t)(b * 8 + hkv) * HD * S_;

  const int q0w = t * 128 + wave * 32;
  const int nsteps = 2 * (t + 1);

  short8 qf[8];
#pragma unroll
  for (int ki = 0; ki < 8; ++ki)
    qf[ki] = *(const short8*)(Q + (size_t)(q0w + ql) * HD + ki * 16 + lh * 8);

  f32x16 o[4];
#pragma unroll
  for (int dt = 0; dt < 4; ++dt) o[dt] = 0.f;
  float m = -1e30f, l = 0.f;

  auto stage = [&](int buf, int kv0) {
#pragma unroll
    for (int inst = 0; inst < 4; ++inst) {
      int pp2 = wave * 4096 + inst * 1024 + lane * 16;
      int row = pp2 >> 8;
      int colb = (pp2 & 255) ^ ((row & 7) << 4);
      load_lds16(Kg + (((size_t)(kv0 + row)) << 7) + (colb >> 1),
                 &Ks[buf][(wave * 4096 + inst * 1024) >> 1]);
    }
#pragma unroll
    for (int inst = 0; inst < 4; ++inst) {
      int pp2 = wave * 4096 + inst * 1024 + lane * 16;
      int d = pp2 >> 7;
      int colb = (pp2 & 127) ^ ((d & 7) << 4);
      load_lds16(Vg + (size_t)d * S_ + kv0 + (colb >> 1),
                 &Vs[buf][(wave * 4096 + inst * 1024) >> 1]);
    }
  };

  stage(0, 0);
  for (int i = 0; i < nsteps; ++i) {
    const int kv0 = i * 64;
    const u16* kb = Ks[i & 1];
    const u16* vb = Vs[i & 1];
    if (i + 1 < nsteps) {
      stage((i + 1) & 1, kv0 + 64);
      ASM_VMCNT(8);
    } else {
      ASM_VMCNT(0);
    }
    __builtin_amdgcn_s_barrier();
    MEMFENCE;                                // loads can't hoist above the barrier

    if (kv0 < q0w + 32) {
      f32x16 sacc[2];
      sacc[0] = 0.f; sacc[1] = 0.f;
      __builtin_amdgcn_s_setprio(1);
#pragma unroll
      for (int ki = 0; ki < 8; ++ki) {
        const int off = ki * 32 + lh * 16;
#pragma unroll
        for (int kvt = 0; kvt < 2; ++kvt) {
          const int row = kvt * 32 + ql;
          short8 kf = *(const short8*)&kb[(row << 7) + ((off ^ ((row & 7) << 4)) >> 1)];
          sacc[kvt] = __builtin_amdgcn_mfma_f32_32x32x16_bf16(kf, qf[ki], sacc[kvt], 0, 0, 0);
        }
      }
      __builtin_amdgcn_s_setprio(0);
      const int q = q0w + ql;
      if (kv0 + 64 > q0w) {
#pragma unroll
        for (int kvt = 0; kvt < 2; ++kvt) {
          const int kvb = kv0 + kvt * 32 + 4 * lh;
#pragma unroll
          for (int reg = 0; reg < 16; ++reg) {
            const int kvr = kvb + (reg & 3) + 8 * (reg >> 2);
            sacc[kvt][reg] = (kvr > q) ? -1e30f : sacc[kvt][reg];
          }
        }
      }
      float mx = sacc[0][0];
#pragma unroll
      for (int kvt = 0; kvt < 2; ++kvt)
#pragma unroll
        for (int reg = 0; reg < 16; ++reg) mx = fmaxf(mx, sacc[kvt][reg]);
      mx = fmaxf(mx, __shfl_xor(mx, 32, 64));
      if (__any(mx > m + RTHR)) {
        float mn = fmaxf(m, mx);
        float sc = exp2f_fast((m - mn) * CEXP);
        l *= sc;
        m = mn;
#pragma unroll
        for (int dt = 0; dt < 4; ++dt)
#pragma unroll
          for (int reg = 0; reg < 16; ++reg) o[dt][reg] *= sc;
      }
      short8 pf[4];
      const float mc = m * CEXP;
      float ps = 0.f;
#pragma unroll
      for (int kvt = 0; kvt < 2; ++kvt) {
        float pv[16];
#pragma unroll
        for (int reg = 0; reg < 16; ++reg) {
          pv[reg] = exp2f_fast(__builtin_fmaf(sacc[kvt][reg], CEXP, -mc));
          ps += pv[reg];
        }
        int A0 = cvtpk(pv[0], pv[1]),  B0 = cvtpk(pv[2], pv[3]);
        int C0 = cvtpk(pv[4], pv[5]),  D0 = cvtpk(pv[6], pv[7]);
        int A1 = cvtpk(pv[8], pv[9]),  B1 = cvtpk(pv[10], pv[11]);
        int C1 = cvtpk(pv[12], pv[13]), D1 = cvtpk(pv[14], pv[15]);
        pl32swap(A0, C0);
        pl32swap(B0, D0);
        pl32swap(A1, C1);
        pl32swap(B1, D1);
        i32x4 w0 = (i32x4){A0, B0, C0, D0};
        i32x4 w1 = (i32x4){A1, B1, C1, D1};
        pf[kvt * 2]     = *(short8*)&w0;
        pf[kvt * 2 + 1] = *(short8*)&w1;
      }
      l += ps;
      __builtin_amdgcn_s_setprio(1);
#pragma unroll
      for (int kc = 0; kc < 4; ++kc) {
        const int off = kc * 32 + lh * 16;
#pragma unroll
        for (int dt = 0; dt < 4; ++dt) {
          const int d = dt * 32 + ql;
          short8 vf = *(const short8*)&vb[(d << 6) + ((off ^ ((d & 7) << 4)) >> 1)];
          o[dt] = __builtin_amdgcn_mfma_f32_32x32x16_bf16(vf, pf[kc], o[dt], 0, 0, 0);
        }
      }
      __builtin_amdgcn_s_setprio(0);
    }
    MEMFENCE;                                // loads can't sink below the barrier
    __builtin_amdgcn_s_barrier();            // buffer consumed; next iter may overwrite
  }

  l += __shfl_xor(l, 32, 64);
  const float inv = 1.0f / l;
  const size_t rowoff = ((size_t)(b * 2048 + q0w + ql)) * 2048 + h * 128;
#pragma unroll
  for (int dt = 0; dt < 4; ++dt)
#pragma unroll
    for (int g = 0; g < 4; ++g) {
      const int d0 = dt * 32 + 8 * g + 4 * lh;
      int w0 = cvtpk(o[dt][4 * g] * inv, o[dt][4 * g + 1] * inv);
      int w1 = cvtpk(o[dt][4 * g + 2] * inv, o[dt][4 * g + 3] * inv);
      i32x2 pk = (i32x2){w0, w1};
      *(i32x2*)((u16*)ao + rowoff + d0) = pk;
    }
}

extern "C" void kernel_launch(void* const* d_in, const int* in_sizes, int n_in,
                              void* d_out, int out_size, void* d_ws, size_t ws_size,
                              hipStream_t stream) {
  const float* x = (const float*)d_in[0];
  const float* fc = (const float*)d_in[1];
  const float* wq = (const float*)d_in[2];
  const float* wk = (const float*)d_in[3];
  const float* wv = (const float*)d_in[4];
  const float* wo = (const float*)d_in[5];
  const float* qw = (const float*)d_in[6];
  const float* kw = (const float*)d_in[7];
  float* out = (float*)d_out;
  char* ws = (char*)d_ws;

  u16* xb    = (u16*)(ws);                 // [4096][2048] bf16   16 MB
  u16* wqkvb = (u16*)(ws + 16777216);      // [4096][2048] bf16   16 MB
  u16* wob   = (u16*)(ws + 33554432);      // [2048][2048] bf16    8 MB
  u16* qrope = (u16*)(ws + 75497472);      // [2][16][2048][128]  16 MB
  u16* krope = (u16*)(ws + 92274688);      // [2][8][2048][128]    8 MB
  u16* vtb   = (u16*)(ws + 100663296);     // [2][8][128][2048]    8 MB
  u16* ao    = (u16*)(ws + 109051904);     // [4096][2048] bf16   16 MB

  cvt_all<<<20480, 256, 0, stream>>>(x, wq, wk, wv, wo, xb, wqkvb, wob);

  gemm_qkv_fused<<<512, 512, 0, stream>>>(xb, wqkvb, fc, qw, kw, qrope, krope, vtb);

  attn7<<<512, 256, 0, stream>>>(qrope, krope, vtb, ao);

  gemm_bt3<1><<<512, 256, 0, stream>>>(ao, wob, (void*)out, 4096, 2048, 2048, 16);
}

// Round 16
// 193.290 us; speedup vs baseline: 1.2846x; 1.0100x over previous
//
#include <hip/hip_runtime.h>

#define B_ 2
#define S_ 2048
#define D_ 2048
#define NH 16
#define NKV 8
#define HD 128
#define SCALE 0.08838834764831845f
#define CEXP 0.1275255f          // SCALE * log2(e)
#define RTHR 62.733f             // 8 / CEXP  (defer-max threshold, p <= 2^8)

typedef unsigned short u16;
typedef __attribute__((ext_vector_type(8))) short short8;
typedef __attribute__((ext_vector_type(4))) float f32x4;
typedef __attribute__((ext_vector_type(16))) float f32x16;
typedef __attribute__((ext_vector_type(4))) int i32x4;
typedef __attribute__((ext_vector_type(2))) int i32x2;

#define ASM_VMCNT(N) asm volatile("s_waitcnt vmcnt(" #N ")" ::: "memory")
#define MEMFENCE asm volatile("" ::: "memory")

__device__ __forceinline__ u16 f2b(float f) {
  union { float f; unsigned u; } c; c.f = f;
  unsigned u = c.u;
  return (u16)((u + 0x7fffu + ((u >> 16) & 1u)) >> 16);
}
__device__ __forceinline__ float b2f(u16 h) {
  union { unsigned u; float f; } c; c.u = ((unsigned)h) << 16;
  return c.f;
}
__device__ __forceinline__ float exp2f_fast(float x) {
  float r; asm("v_exp_f32 %0, %1" : "=v"(r) : "v"(x)); return r;
}
__device__ __forceinline__ int cvtpk(float a, float b) {  // low16=bf16(a), high16=bf16(b)
  int r; asm("v_cvt_pk_bf16_f32 %0, %1, %2" : "=v"(r) : "v"(a), "v"(b)); return r;
}
// swap: a.hi32lanes <-> b.lo32lanes (both regs updated)
__device__ __forceinline__ void pl32swap(int& a, int& b) {
  asm volatile("v_permlane32_swap_b32 %0, %1" : "+v"(a), "+v"(b));
}

__device__ __forceinline__ void load_lds16(const u16* g, u16* l) {
  __builtin_amdgcn_global_load_lds(
      (const __attribute__((address_space(1))) unsigned int*)g,
      (__attribute__((address_space(3))) unsigned int*)l, 16, 0, 0);
}

// ---------------- fused f32 -> bf16 conversion (all 5 tensors, 1 launch) ----------------
__global__ __launch_bounds__(256) void cvt_all(const float* __restrict__ x,
                                               const float* __restrict__ wq,
                                               const float* __restrict__ wk,
                                               const float* __restrict__ wv,
                                               const float* __restrict__ wo,
                                               u16* __restrict__ xb,
                                               u16* __restrict__ wqkvb,
                                               u16* __restrict__ wob) {
  const int blk = blockIdx.x;
  const float* src; u16* dst; int base;
  if (blk < 8192)       { src = x;  dst = xb;                  base = blk; }
  else if (blk < 12288) { src = wq; dst = wqkvb;               base = blk - 8192; }
  else if (blk < 14336) { src = wk; dst = wqkvb + 2048 * 2048; base = blk - 12288; }
  else if (blk < 16384) { src = wv; dst = wqkvb + 3072 * 2048; base = blk - 14336; }
  else                  { src = wo; dst = wob;                 base = blk - 16384; }
  int i = base * 256 + threadIdx.x;
  float4 v = ((const float4*)src)[i];
  u16 o0 = f2b(v.x), o1 = f2b(v.y), o2 = f2b(v.z), o3 = f2b(v.w);
  unsigned long long packed = (unsigned long long)o0 | ((unsigned long long)o1 << 16) |
                              ((unsigned long long)o2 << 32) | ((unsigned long long)o3 << 48);
  ((unsigned long long*)dst)[i] = packed;
}

// ---------------- QKV GEMM + fused RMSNorm/RoPE/V-transpose epilogue ----------------
#define LDA4Q(dst, SRC) \
  { _Pragma("unroll") for (int i2 = 0; i2 < 4; ++i2) { \
      const int arow = wr * 64 + i2 * 16 + r; \
      dst[i2] = *(const short8*)&(SRC)[arow * 32 + ((hi ^ ((arow >> 1) & 3)) << 3)]; } }
#define LDB4Q(dst, SRC) \
  { _Pragma("unroll") for (int n2 = 0; n2 < 4; ++n2) { \
      const int brow = wc * 64 + n2 * 16 + r; \
      dst[n2] = *(const short8*)&(SRC)[brow * 32 + ((hi ^ ((brow >> 1) & 3)) << 3)]; } }
#define MFMA16Q(AF, BF) \
  { __builtin_amdgcn_s_setprio(1); \
    _Pragma("unroll") for (int i2 = 0; i2 < 4; ++i2) \
    _Pragma("unroll") for (int n2 = 0; n2 < 4; ++n2) \
      acc[i2][n2] = __builtin_amdgcn_mfma_f32_16x16x32_bf16(AF[i2], BF[n2], acc[i2][n2], 0, 0, 0); \
    __builtin_amdgcn_s_setprio(0); }

__global__ __launch_bounds__(512, 4) void gemm_qkv_fused(const u16* __restrict__ A,
                                                         const u16* __restrict__ Bm,
                                                         const float* __restrict__ fc,
                                                         const float* __restrict__ qw,
                                                         const float* __restrict__ kw,
                                                         u16* __restrict__ qrope,
                                                         u16* __restrict__ krope,
                                                         u16* __restrict__ vt) {
  __shared__ __align__(16) u16 As2[2][8192];   // [kc][256 rows x 32 k]  32 KB
  __shared__ __align__(16) u16 Bs2[2][4096];   // [kc][128 rows x 32 k]  16 KB
  __shared__ float sq[2][256];                 // cross-wave sumsq exchange  2 KB
  const int tid = threadIdx.x;
  const int wave = tid >> 6, lane = tid & 63;
  const int L = (blockIdx.x & 7) * 64 + (blockIdx.x >> 3);  // bijective XCD chunking
  const int bm = L >> 5, bn = L & 31;          // 16 x 32 tile grid
  const int wr = wave >> 1, wc = wave & 1;     // 4M x 2N waves; per-wave 64x64
  const int r = lane & 15, hi = lane >> 4;
  const int rowA0 = bm * 256, rowB0 = bn * 128;

  f32x4 acc[4][4];
#pragma unroll
  for (int mi = 0; mi < 4; ++mi)
#pragma unroll
    for (int ni = 0; ni < 4; ++ni) acc[mi][ni] = (f32x4){0.f, 0.f, 0.f, 0.f};

  auto stage_ha = [&](u16* lds, int kcol) {
#pragma unroll
    for (int l = 0; l < 2; ++l) {
      const int p = wave * 2048 + l * 1024 + lane * 16;
      const int row = p >> 6, slot = (p >> 4) & 3;
      const int kg = slot ^ ((row >> 1) & 3);
      load_lds16(A + (size_t)(rowA0 + row) * 2048 + kcol + kg * 8,
                 lds + ((wave * 2048 + l * 1024) >> 1));
    }
  };
  auto stage_hb = [&](u16* lds, int kcol) {
    const int p = wave * 1024 + lane * 16;
    const int row = p >> 6, slot = (p >> 4) & 3;
    const int kg = slot ^ ((row >> 1) & 3);
    load_lds16(Bm + (size_t)(rowB0 + row) * 2048 + kcol + kg * 8,
               lds + ((wave * 1024) >> 1));
  };

  for (int kt = 0; kt < 32; ++kt) {
    const int k0 = kt << 6;
    stage_ha(As2[0], k0);
    stage_hb(Bs2[0], k0);
    stage_ha(As2[1], k0 + 32);
    stage_hb(Bs2[1], k0 + 32);
    ASM_VMCNT(0);
    __builtin_amdgcn_s_barrier();
    MEMFENCE;
    short8 af[4], bf[4];
    LDB4Q(bf, Bs2[0]); LDA4Q(af, As2[0]);
    MFMA16Q(af, bf);
    LDB4Q(bf, Bs2[1]); LDA4Q(af, As2[1]);
    MFMA16Q(af, bf);
    MEMFENCE;
    __builtin_amdgcn_s_barrier();   // all reads done before next stage overwrites
  }

  // ---- fused epilogue ----
  if (bn >= 24) {
    // V head: no norm/rope; store transposed vt[(b*8+hv)*128+d][s]
    const int hv = bn - 24;
#pragma unroll
    for (int mi = 0; mi < 4; ++mi) {
      const int tok0 = bm * 256 + wr * 64 + mi * 16 + hi * 4;
      const int bb = tok0 >> 11, sl = tok0 & 2047;
#pragma unroll
      for (int ni = 0; ni < 4; ++ni) {
        const int d = wc * 64 + ni * 16 + r;
        int w0 = cvtpk(acc[mi][ni][0], acc[mi][ni][1]);
        int w1 = cvtpk(acc[mi][ni][2], acc[mi][ni][3]);
        i32x2 pk = (i32x2){w0, w1};
        *(i32x2*)(vt + ((size_t)(bb * 8 + hv) * 128 + d) * 2048 + sl) = pk;
      }
    }
  } else {
    // Q/K head: RMSNorm over the 128-col row, then RoPE, then store.
    const float* nw = (bn < 16) ? qw : kw;
    float nwv[4];
#pragma unroll
    for (int ni = 0; ni < 4; ++ni) nwv[ni] = nw[wc * 64 + ni * 16 + r];
    float ssq[4][4];
#pragma unroll
    for (int mi = 0; mi < 4; ++mi)
#pragma unroll
      for (int r2 = 0; r2 < 4; ++r2) {
        float s4 = 0.f;
#pragma unroll
        for (int ni = 0; ni < 4; ++ni) {
          float a = acc[mi][ni][r2];
          s4 = __builtin_fmaf(a, a, s4);
        }
#pragma unroll
        for (int mk = 1; mk < 16; mk <<= 1) s4 += __shfl_xor(s4, mk, 64);
        ssq[mi][r2] = s4;
      }
    if (r == 0) {
#pragma unroll
      for (int mi = 0; mi < 4; ++mi)
#pragma unroll
        for (int r2 = 0; r2 < 4; ++r2)
          sq[wc][wr * 64 + mi * 16 + hi * 4 + r2] = ssq[mi][r2];
    }
    __syncthreads();   // block-uniform branch (bn uniform) -> safe
    u16* outp = (bn < 16) ? qrope : krope;
#pragma unroll
    for (int mi = 0; mi < 4; ++mi) {
      const int tok0 = bm * 256 + wr * 64 + mi * 16 + hi * 4;
      const int bb = tok0 >> 11;
      const size_t headbase = (bn < 16) ? ((size_t)(bb * 16 + bn) * 2048)
                                        : ((size_t)(bb * 8 + (bn - 16)) * 2048);
#pragma unroll
      for (int r2 = 0; r2 < 4; ++r2) {
        const int sl = (tok0 + r2) & 2047;
        const float tot = ssq[mi][r2] + sq[wc ^ 1][wr * 64 + mi * 16 + hi * 4 + r2];
        const float rms = rsqrtf(tot * (1.0f / 128.0f) + 1e-6f);
#pragma unroll
        for (int ni = 0; ni < 4; ++ni) {
          const int d = wc * 64 + ni * 16 + r;
          float val = acc[mi][ni][r2] * rms * nwv[ni];
          float prt = __shfl_xor(val, 1, 64);
          const float2 cs = *(const float2*)&fc[(size_t)(sl * 64 + (d >> 1)) * 2];
          float outv = (r & 1) ? (prt * cs.y + val * cs.x)     // odd col: tr*sin + ti*cos
                               : (val * cs.x - prt * cs.y);    // even col: tr*cos - ti*sin
          outp[(headbase + sl) * 128 + d] = f2b(outv);
        }
      }
    }
  }
}

// ---------------- out-GEMM (128^2): single-buffer LDS, co-resident blocks ----------
template<int OUTF32>
__global__ __launch_bounds__(256, 4) void gemm_bt3(const u16* __restrict__ A, const u16* __restrict__ Bm,
                                                   void* __restrict__ Cv, int M, int N, int K, int nbn) {
  __shared__ __align__(16) u16 As[128 * 64];   // 16 KB
  __shared__ __align__(16) u16 Bs[128 * 64];   // 16 KB
  const int tid = threadIdx.x;
  const int wave = tid >> 6, lane = tid & 63;
  const int nwg = gridDim.x, cpx = nwg >> 3;
  const int L = (blockIdx.x & 7) * cpx + (blockIdx.x >> 3);
  const int bm = L / nbn, bn = L % nbn;
  const int wr = wave >> 1, wc = wave & 1;
  const int r = lane & 15, hi = lane >> 4;

  f32x4 acc[4][4];
#pragma unroll
  for (int m = 0; m < 4; ++m)
#pragma unroll
    for (int n = 0; n < 4; ++n) acc[m][n] = (f32x4){0.f, 0.f, 0.f, 0.f};

  const int gslot = (lane & 7) ^ (lane >> 3);
  const int srow = lane >> 3;

  auto stage = [&](int k0) {
#pragma unroll
    for (int jj = 0; jj < 4; ++jj) {
      int j = wave * 4 + jj;
      int row = j * 8 + srow;
      load_lds16(A + (size_t)(bm * 128 + row) * K + k0 + gslot * 8, &As[j * 512]);
      load_lds16(Bm + (size_t)(bn * 128 + row) * K + k0 + gslot * 8, &Bs[j * 512]);
    }
  };

  const int nk = K >> 6;
  for (int kt = 0; kt < nk; ++kt) {
    stage(kt << 6);
    ASM_VMCNT(0);
    __builtin_amdgcn_s_barrier();
    MEMFENCE;
#pragma unroll
    for (int kc = 0; kc < 2; ++kc) {
      short8 af[4], bfr[4];
#pragma unroll
      for (int m = 0; m < 4; ++m) {
        int row = wr * 64 + m * 16 + r;
        int slot = (hi + kc * 4) ^ (row & 7);
        af[m] = *(const short8*)&As[row * 64 + slot * 8];
      }
#pragma unroll
      for (int n = 0; n < 4; ++n) {
        int row = wc * 64 + n * 16 + r;
        int slot = (hi + kc * 4) ^ (row & 7);
        bfr[n] = *(const short8*)&Bs[row * 64 + slot * 8];
      }
#pragma unroll
      for (int m = 0; m < 4; ++m)
#pragma unroll
        for (int n = 0; n < 4; ++n)
          acc[m][n] = __builtin_amdgcn_mfma_f32_16x16x32_bf16(af[m], bfr[n], acc[m][n], 0, 0, 0);
    }
    MEMFENCE;
    __builtin_amdgcn_s_barrier();   // reads done before next stage overwrites
  }

#pragma unroll
  for (int m = 0; m < 4; ++m)
#pragma unroll
    for (int n = 0; n < 4; ++n)
#pragma unroll
      for (int r2 = 0; r2 < 4; ++r2) {
        int grow = bm * 128 + wr * 64 + m * 16 + hi * 4 + r2;
        int gcol = bn * 128 + wc * 64 + n * 16 + r;
        if (OUTF32)
          ((float*)Cv)[(size_t)grow * N + gcol] = acc[m][n][r2];
        else
          ((u16*)Cv)[(size_t)grow * N + gcol] = f2b(acc[m][n][r2]);
      }
}

// ---------------- causal flash attention v9: ONE barrier per step ----------------
// Race-free single-barrier loop: [vmcnt(0) -> s_barrier -> stage(i+1) -> compute(i)].
// (1) read-ready: each wave drains its stage(i) loads (issued one compute-phase ago,
//     wait ~free) BEFORE the barrier -> after barrier all of buf[i&1] is visible.
// (2) anti-dep: stage(i+2) targets buf[i&1] but issues only after barrier(i+1), which
//     every wave passes only after finishing compute(i)'s reads (program order).
__global__ __launch_bounds__(256, 2) void attn9(const u16* __restrict__ qr, const u16* __restrict__ kr,
                                                const u16* __restrict__ vt, u16* __restrict__ ao) {
  __shared__ __align__(16) u16 Ks[2][64 * 128];
  __shared__ __align__(16) u16 Vs[2][128 * 64];
  const int tid = threadIdx.x, wave = tid >> 6, lane = tid & 63;
  const int ql = lane & 31, lh = lane >> 5;

  const int blk = blockIdx.x;
  const int half = blk >> 8;                 // 0: big tiles, 1: complementary small tiles
  const int xcd = blk & 7;
  const int idx = (blk >> 3) & 31;
  const int bh = xcd * 4 + (idx & 3);
  const int pp = idx >> 2;                   // 0..7
  const int t = half ? pp : 15 - pp;
  const int b = bh >> 4, h = bh & 15, hkv = h >> 1;

  const u16* Q  = qr + (size_t)(b * 16 + h) * S_ * HD;
  const u16* Kg = kr + (size_t)(b * 8 + hkv) * S_ * HD;
  const u16* Vg = vt + (size_t)(b * 8 + hkv) * HD * S_;

  const int q0w = t * 128 + wave * 32;
  const int nsteps = 2 * (t + 1);

  short8 qf[8];
#pragma unroll
  for (int ki = 0; ki < 8; ++ki)
    qf[ki] = *(const short8*)(Q + (size_t)(q0w + ql) * HD + ki * 16 + lh * 8);

  f32x16 o[4];
#pragma unroll
  for (int dt = 0; dt < 4; ++dt) o[dt] = 0.f;
  float m = -1e30f, l = 0.f;

  auto stage = [&](int buf, int kv0) {
#pragma unroll
    for (int inst = 0; inst < 4; ++inst) {
      int pp2 = wave * 4096 + inst * 1024 + lane * 16;
      int row = pp2 >> 8;
      int colb = (pp2 & 255) ^ ((row & 7) << 4);
      load_lds16(Kg + (((size_t)(kv0 + row)) << 7) + (colb >> 1),
                 &Ks[buf][(wave * 4096 + inst * 1024) >> 1]);
    }
#pragma unroll
    for (int inst = 0; inst < 4; ++inst) {
      int pp2 = wave * 4096 + inst * 1024 + lane * 16;
      int d = pp2 >> 7;
      int colb = (pp2 & 127) ^ ((d & 7) << 4);
      load_lds16(Vg + (size_t)d * S_ + kv0 + (colb >> 1),
                 &Vs[buf][(wave * 4096 + inst * 1024) >> 1]);
    }
  };

  stage(0, 0);
  for (int i = 0; i < nsteps; ++i) {
    const int kv0 = i * 64;
    const u16* kb = Ks[i & 1];
    const u16* vb = Vs[i & 1];

    ASM_VMCNT(0);                            // my stage(i) loads (issued last iter) done
    __builtin_amdgcn_s_barrier();            // everyone's drained; prev compute reads done
    MEMFENCE;                                // compute reads can't hoist above barrier
    if (i + 1 < nsteps) stage((i + 1) & 1, kv0 + 64);   // prefetch hides under compute(i)

    if (kv0 < q0w + 32) {
      f32x16 sacc[2];
      sacc[0] = 0.f; sacc[1] = 0.f;
      __builtin_amdgcn_s_setprio(1);
#pragma unroll
      for (int ki = 0; ki < 8; ++ki) {
        const int off = ki * 32 + lh * 16;
#pragma unroll
        for (int kvt = 0; kvt < 2; ++kvt) {
          const int row = kvt * 32 + ql;
          short8 kf = *(const short8*)&kb[(row << 7) + ((off ^ ((row & 7) << 4)) >> 1)];
          sacc[kvt] = __builtin_amdgcn_mfma_f32_32x32x16_bf16(kf, qf[ki], sacc[kvt], 0, 0, 0);
        }
      }
      __builtin_amdgcn_s_setprio(0);
      const int q = q0w + ql;
      if (kv0 + 64 > q0w) {
#pragma unroll
        for (int kvt = 0; kvt < 2; ++kvt) {
          const int kvb = kv0 + kvt * 32 + 4 * lh;
#pragma unroll
          for (int reg = 0; reg < 16; ++reg) {
            const int kvr = kvb + (reg & 3) + 8 * (reg >> 2);
            sacc[kvt][reg] = (kvr > q) ? -1e30f : sacc[kvt][reg];
          }
        }
      }
      float mx = sacc[0][0];
#pragma unroll
      for (int kvt = 0; kvt < 2; ++kvt)
#pragma unroll
        for (int reg = 0; reg < 16; ++reg) mx = fmaxf(mx, sacc[kvt][reg]);
      mx = fmaxf(mx, __shfl_xor(mx, 32, 64));
      if (__any(mx > m + RTHR)) {
        float mn = fmaxf(m, mx);
        float sc = exp2f_fast((m - mn) * CEXP);
        l *= sc;
        m = mn;
#pragma unroll
        for (int dt = 0; dt < 4; ++dt)
#pragma unroll
          for (int reg = 0; reg < 16; ++reg) o[dt][reg] *= sc;
      }
      short8 pf[4];
      const float mc = m * CEXP;
      float ps = 0.f;
#pragma unroll
      for (int kvt = 0; kvt < 2; ++kvt) {
        float pv[16];
#pragma unroll
        for (int reg = 0; reg < 16; ++reg) {
          pv[reg] = exp2f_fast(__builtin_fmaf(sacc[kvt][reg], CEXP, -mc));
          ps += pv[reg];
        }
        int A0 = cvtpk(pv[0], pv[1]),  B0 = cvtpk(pv[2], pv[3]);
        int C0 = cvtpk(pv[4], pv[5]),  D0 = cvtpk(pv[6], pv[7]);
        int A1 = cvtpk(pv[8], pv[9]),  B1 = cvtpk(pv[10], pv[11]);
        int C1 = cvtpk(pv[12], pv[13]), D1 = cvtpk(pv[14], pv[15]);
        pl32swap(A0, C0);
        pl32swap(B0, D0);
        pl32swap(A1, C1);
        pl32swap(B1, D1);
        i32x4 w0 = (i32x4){A0, B0, C0, D0};
        i32x4 w1 = (i32x4){A1, B1, C1, D1};
        pf[kvt * 2]     = *(short8*)&w0;
        pf[kvt * 2 + 1] = *(short8*)&w1;
      }
      l += ps;
      __builtin_amdgcn_s_setprio(1);
#pragma unroll
      for (int kc = 0; kc < 4; ++kc) {
        const int off = kc * 32 + lh * 16;
#pragma unroll
        for (int dt = 0; dt < 4; ++dt) {
          const int d = dt * 32 + ql;
          short8 vf = *(const short8*)&vb[(d << 6) + ((off ^ ((d & 7) << 4)) >> 1)];
          o[dt] = __builtin_amdgcn_mfma_f32_32x32x16_bf16(vf, pf[kc], o[dt], 0, 0, 0);
        }
      }
      __builtin_amdgcn_s_setprio(0);
    }
    MEMFENCE;                                // compute reads can't sink below next barrier
  }

  l += __shfl_xor(l, 32, 64);
  const float inv = 1.0f / l;
  const size_t rowoff = ((size_t)(b * 2048 + q0w + ql)) * 2048 + h * 128;
#pragma unroll
  for (int dt = 0; dt < 4; ++dt)
#pragma unroll
    for (int g = 0; g < 4; ++g) {
      const int d0 = dt * 32 + 8 * g + 4 * lh;
      int w0 = cvtpk(o[dt][4 * g] * inv, o[dt][4 * g + 1] * inv);
      int w1 = cvtpk(o[dt][4 * g + 2] * inv, o[dt][4 * g + 3] * inv);
      i32x2 pk = (i32x2){w0, w1};
      *(i32x2*)((u16*)ao + rowoff + d0) = pk;
    }
}

extern "C" void kernel_launch(void* const* d_in, const int* in_sizes, int n_in,
                              void* d_out, int out_size, void* d_ws, size_t ws_size,
                              hipStream_t stream) {
  const float* x = (const float*)d_in[0];
  const float* fc = (const float*)d_in[1];
  const float* wq = (const float*)d_in[2];
  const float* wk = (const float*)d_in[3];
  const float* wv = (const float*)d_in[4];
  const float* wo = (const float*)d_in[5];
  const float* qw = (const float*)d_in[6];
  const float* kw = (const float*)d_in[7];
  float* out = (float*)d_out;
  char* ws = (char*)d_ws;

  u16* xb    = (u16*)(ws);                 // [4096][2048] bf16   16 MB
  u16* wqkvb = (u16*)(ws + 16777216);      // [4096][2048] bf16   16 MB
  u16* wob   = (u16*)(ws + 33554432);      // [2048][2048] bf16    8 MB
  u16* qrope = (u16*)(ws + 75497472);      // [2][16][2048][128]  16 MB
  u16* krope = (u16*)(ws + 92274688);      // [2][8][2048][128]    8 MB
  u16* vtb   = (u16*)(ws + 100663296);     // [2][8][128][2048]    8 MB
  u16* ao    = (u16*)(ws + 109051904);     // [4096][2048] bf16   16 MB

  cvt_all<<<20480, 256, 0, stream>>>(x, wq, wk, wv, wo, xb, wqkvb, wob);

  gemm_qkv_fused<<<512, 512, 0, stream>>>(xb, wqkvb, fc, qw, kw, qrope, krope, vtb);

  attn9<<<512, 256, 0, stream>>>(qrope, krope, vtb, ao);

  gemm_bt3<1><<<512, 256, 0, stream>>>(ao, wob, (void*)out, 4096, 2048, 2048, 16);
}